// Round 8
// baseline (173.244 us; speedup 1.0000x reference)
//
#include <hip/hip_runtime.h>

#define CCH   256
#define NSEQ  4096
#define NH    8
#define HD    32

typedef short s8x __attribute__((ext_vector_type(8)));
typedef float f4x __attribute__((ext_vector_type(4)));

__device__ __forceinline__ f4x mfma16(s8x a, s8x b, f4x c) {
  return __builtin_amdgcn_mfma_f32_16x16x32_bf16(a, b, c, 0, 0, 0);
}

__device__ __forceinline__ unsigned short f2bf(float f) {
  union { float f; unsigned int u; } v; v.f = f;
  unsigned int u = v.u + 0x7fffu + ((v.u >> 16) & 1u);
  return (unsigned short)(u >> 16);
}

__device__ __forceinline__ unsigned int pk_bf_rnd(float lo, float hi) {
  return (unsigned int)f2bf(lo) | ((unsigned int)f2bf(hi) << 16);
}

// pack two f32 -> one u32 of bf16 (truncating; P >= 0 so safe)
__device__ __forceinline__ unsigned int pk_bf_trunc(float lo, float hi) {
  union { float f; unsigned int u; } a, b; a.f = lo; b.f = hi;
  return __builtin_amdgcn_perm(b.u, a.u, 0x07060302);
}

// raw v_exp_f32
#if defined(__has_builtin)
#if __has_builtin(__builtin_amdgcn_exp2f)
#define FEXP2(x) __builtin_amdgcn_exp2f(x)
#endif
#endif
#ifndef FEXP2
__device__ __forceinline__ float __fexp2_asm(float x) {
  float r; asm("v_exp_f32 %0, %1" : "=v"(r) : "v"(x)); return r;
}
#define FEXP2(x) __fexp2_asm(x)
#endif

#define C2SCALE (0.17677669529663689f * 1.4426950408889634f)

// ---------------- LayerNorm + transpose, with cvt_weights folded in ----------------
// blocks 0..255: ln (32 positions each); blocks 256..511: weight fp32->bf16.
__global__ __launch_bounds__(256) void ln_cvt_kernel(const float* __restrict__ x,
                                                     const float* __restrict__ nw,
                                                     const float* __restrict__ nb,
                                                     unsigned short* __restrict__ xn,
                                                     const float* __restrict__ qw,
                                                     const float* __restrict__ pw,
                                                     unsigned short* __restrict__ qwb,
                                                     unsigned short* __restrict__ pwb) {
  if (blockIdx.x >= 256) {
    const int t = (blockIdx.x - 256) * 256 + threadIdx.x;   // 0..65535
    const float4* src;
    unsigned short* dst;
    int idx;
    if (t < 49152) { src = reinterpret_cast<const float4*>(qw); dst = qwb; idx = t; }
    else           { src = reinterpret_cast<const float4*>(pw); dst = pwb; idx = t - 49152; }
    const float4 vv = src[idx];
    union { unsigned short u[4]; uint2 v; } pk;
    pk.u[0] = f2bf(vv.x); pk.u[1] = f2bf(vv.y); pk.u[2] = f2bf(vv.z); pk.u[3] = f2bf(vv.w);
    *reinterpret_cast<uint2*>(dst + 4 * idx) = pk.v;
    return;
  }

  __shared__ float Ls[256 * 32];
  __shared__ float Sred[2][32][8];
  __shared__ float Mrs[32][2];
  const int t  = threadIdx.x;
  const int n  = t & 31;
  const int cg = t >> 5;
  const int p0 = blockIdx.x * 32;
  const int b  = p0 >> 12;
  const int n0 = p0 & 4095;
  const float* xb = x + (size_t)b * CCH * NSEQ + n0;

  #pragma unroll
  for (int i = 0; i < 32; ++i) {
    const int c = i * 8 + cg;
    Ls[c * 32 + (n ^ (c & 31))] = xb[(size_t)c * NSEQ + n];
  }
  __syncthreads();

  float s = 0.f, sq = 0.f;
  #pragma unroll
  for (int j = 0; j < 32; ++j) {
    const int c = cg * 32 + j;
    const float v = Ls[c * 32 + (n ^ j)];
    s += v; sq += v * v;
  }
  Sred[0][n][cg] = s; Sred[1][n][cg] = sq;
  __syncthreads();
  float ts = 0.f, tq = 0.f;
  #pragma unroll
  for (int g = 0; g < 8; ++g) { ts += Sred[0][n][g]; tq += Sred[1][n][g]; }
  const float mean = ts * (1.f / 256.f);
  const float rstd = rsqrtf(tq * (1.f / 256.f) - mean * mean + 1e-5f);
  if (cg == 0) { Mrs[n][0] = mean; Mrs[n][1] = rstd; }
  __syncthreads();

  // coalesced write phase: thread -> (row n2, col-block c8b)
  const int n2  = t >> 3;        // 0..31
  const int c8b = t & 7;
  const float mean2 = Mrs[n2][0];
  const float rstd2 = Mrs[n2][1];
  unsigned short* orow = xn + ((size_t)b * NSEQ + n0 + n2) * CCH;
  #pragma unroll
  for (int j8 = 0; j8 < 4; ++j8) {
    const int cb = (j8 * 8 + c8b) * 8;        // 0..248, step 8
    unsigned int w_[4];
    #pragma unroll
    for (int hw = 0; hw < 4; ++hw) {
      const int c = cb + hw * 2;
      const float v0 = Ls[c * 32 + (n2 ^ (c & 31))];
      const float v1 = Ls[(c + 1) * 32 + (n2 ^ ((c + 1) & 31))];
      const float y0 = (v0 - mean2) * rstd2 * nw[c] + nb[c];
      const float y1 = (v1 - mean2) * rstd2 * nw[c + 1] + nb[c + 1];
      w_[hw] = pk_bf_rnd(y0, y1);
    }
    uint4 pkv; pkv.x = w_[0]; pkv.y = w_[1]; pkv.z = w_[2]; pkv.w = w_[3];
    *reinterpret_cast<uint4*>(orow + cb) = pkv;
  }
}

// ======== R8 pipelined GEMM core: 128m x 64n tile, BK=64, K=256 ========
// Double-buffered A/B LDS tiles in a 48KB pool + loop-carried reg staging
// (load kb+2 -> regs, ds_write kb+1, MFMA on kb, ONE barrier/iter) -- the
// R5-proven fa pattern applied to the GEMMs. Identical MFMA order/operands
// to the old GEMM_CORE -> bit-identical results.
// Pool layout (shorts): As0[0,8192) As1[8192,16384) Bs0[16384,20480) Bs1[20480,24576)
#define GEMM_CORE2(A_PTR, B_PTR, ACC)                                           \
  {                                                                             \
    unsigned short* const As0_ = Pool;                                          \
    unsigned short* const As1_ = Pool + 8192;                                   \
    unsigned short* const Bs0_ = Pool + 16384;                                  \
    unsigned short* const Bs1_ = Pool + 20480;                                  \
    const int tr = tid >> 3, c8 = tid & 7;                                      \
    uint4 ra[4], rb[2];                                                         \
    /* prologue: stage kb=0, then issue kb=1 loads */                           \
    _Pragma("unroll")                                                           \
    for (int j = 0; j < 4; ++j)                                                 \
      ra[j] = *reinterpret_cast<const uint4*>(A_PTR + (size_t)(mt * 128 + j * 32 + tr) * CCH + c8 * 8); \
    _Pragma("unroll")                                                           \
    for (int j = 0; j < 2; ++j)                                                 \
      rb[j] = *reinterpret_cast<const uint4*>(B_PTR + (size_t)(nt * 64 + j * 32 + tr) * CCH + c8 * 8);  \
    _Pragma("unroll")                                                           \
    for (int j = 0; j < 4; ++j) {                                               \
      const int ar = j * 32 + tr;                                               \
      *reinterpret_cast<uint4*>(&As0_[ar * 64 + ((c8 ^ (ar & 7)) << 3)]) = ra[j]; \
    }                                                                           \
    _Pragma("unroll")                                                           \
    for (int j = 0; j < 2; ++j) {                                               \
      const int br = j * 32 + tr;                                               \
      *reinterpret_cast<uint4*>(&Bs0_[br * 64 + ((c8 ^ (br & 7)) << 3)]) = rb[j]; \
    }                                                                           \
    _Pragma("unroll")                                                           \
    for (int j = 0; j < 4; ++j)                                                 \
      ra[j] = *reinterpret_cast<const uint4*>(A_PTR + (size_t)(mt * 128 + j * 32 + tr) * CCH + 64 + c8 * 8); \
    _Pragma("unroll")                                                           \
    for (int j = 0; j < 2; ++j)                                                 \
      rb[j] = *reinterpret_cast<const uint4*>(B_PTR + (size_t)(nt * 64 + j * 32 + tr) * CCH + 64 + c8 * 8);  \
    __syncthreads();                                                            \
    for (int kb = 0; kb < 4; ++kb) {                                            \
      unsigned short* const Asc_ = (kb & 1) ? As1_ : As0_;                      \
      unsigned short* const Bsc_ = (kb & 1) ? Bs1_ : Bs0_;                      \
      unsigned short* const Asn_ = (kb & 1) ? As0_ : As1_;                      \
      unsigned short* const Bsn_ = (kb & 1) ? Bs0_ : Bs1_;                      \
      /* write staged tile kb+1 into back buffer */                             \
      if (kb + 1 < 4) {                                                         \
        _Pragma("unroll")                                                       \
        for (int j = 0; j < 4; ++j) {                                           \
          const int ar = j * 32 + tr;                                           \
          *reinterpret_cast<uint4*>(&Asn_[ar * 64 + ((c8 ^ (ar & 7)) << 3)]) = ra[j]; \
        }                                                                       \
        _Pragma("unroll")                                                       \
        for (int j = 0; j < 2; ++j) {                                           \
          const int br = j * 32 + tr;                                           \
          *reinterpret_cast<uint4*>(&Bsn_[br * 64 + ((c8 ^ (br & 7)) << 3)]) = rb[j]; \
        }                                                                       \
      }                                                                         \
      /* issue loads for kb+2 (loop-carried, cannot be sunk) */                 \
      if (kb + 2 < 4) {                                                         \
        _Pragma("unroll")                                                       \
        for (int j = 0; j < 4; ++j)                                             \
          ra[j] = *reinterpret_cast<const uint4*>(A_PTR + (size_t)(mt * 128 + j * 32 + tr) * CCH + (kb + 2) * 64 + c8 * 8); \
        _Pragma("unroll")                                                       \
        for (int j = 0; j < 2; ++j)                                             \
          rb[j] = *reinterpret_cast<const uint4*>(B_PTR + (size_t)(nt * 64 + j * 32 + tr) * CCH + (kb + 2) * 64 + c8 * 8);  \
      }                                                                         \
      /* MFMA on front buffer */                                                \
      _Pragma("unroll")                                                         \
      for (int kin = 0; kin < 2; ++kin) {                                       \
        const int chx = ((kin * 4 + quad) ^ (l16 & 7)) << 3;                    \
        const s8x a0 = *reinterpret_cast<const s8x*>(&Asc_[(wv * 32 + l16) * 64 + chx]);      \
        const s8x a1 = *reinterpret_cast<const s8x*>(&Asc_[(wv * 32 + 16 + l16) * 64 + chx]); \
        _Pragma("unroll")                                                       \
        for (int ni = 0; ni < 4; ++ni) {                                        \
          const s8x bf = *reinterpret_cast<const s8x*>(&Bsc_[(ni * 16 + l16) * 64 + chx]);    \
          ACC[0][ni] = mfma16(a0, bf, ACC[0][ni]);                              \
          ACC[1][ni] = mfma16(a1, bf, ACC[1][ni]);                              \
        }                                                                       \
      }                                                                         \
      __syncthreads();                                                          \
    }                                                                           \
  }

// ---------------- QKV GEMM (tiled, pipelined) ----------------
// Ts (transpose tile for coalesced q/k stores) aliases Pool: only used after
// the final barrier of GEMM_CORE2, so no hazard. LDS = 48KB -> 3 blocks/CU.
__global__ __launch_bounds__(256, 3) void qkv_gemm(const unsigned short* __restrict__ xn,
                                                   const unsigned short* __restrict__ w,
                                                   const float* __restrict__ bias,
                                                   unsigned short* __restrict__ q,
                                                   unsigned short* __restrict__ k,
                                                   unsigned short* __restrict__ vt) {
  __shared__ __align__(16) unsigned short Pool[24576];
  const int tid = threadIdx.x;
  const int wv  = tid >> 6;
  const int lane = tid & 63;
  const int quad = lane >> 4, l16 = lane & 15;
  const int mt = blockIdx.x;
  const int nt = blockIdx.y;

  f4x acc[2][4];
  #pragma unroll
  for (int mi = 0; mi < 2; ++mi)
    #pragma unroll
    for (int ni = 0; ni < 4; ++ni)
      acc[mi][ni] = (f4x){0.f, 0.f, 0.f, 0.f};

  GEMM_CORE2(xn, w, acc)

  const int sel = nt >> 2;                  // wave-uniform: 0=q 1=k 2=v
  if (sel == 2) {
    #pragma unroll
    for (int ni = 0; ni < 4; ++ni) {
      const int o = nt * 64 + ni * 16 + l16;
      const float bs = bias[o];
      const int ol = o & 255;
      const int head = ol >> 5, d = ol & 31;
      #pragma unroll
      for (int mi = 0; mi < 2; ++mi) {
        const int g0 = mt * 128 + wv * 32 + mi * 16 + quad * 4;
        const int bb = g0 >> 12, n0 = g0 & 4095;
        unsigned short* vp = vt + ((size_t)(bb * NH + head) * HD + d) * NSEQ + n0;
        uint2 pk;
        pk.x = pk_bf_rnd(acc[mi][ni][0] + bs, acc[mi][ni][1] + bs);
        pk.y = pk_bf_rnd(acc[mi][ni][2] + bs, acc[mi][ni][3] + bs);
        *reinterpret_cast<uint2*>(vp) = pk;
      }
    }
  } else {
    unsigned short* const Ts = Pool;        // alias; GEMM_CORE2 finished (barrier)
    const float sc = (sel == 0) ? C2SCALE : 1.f;
    unsigned short* base = (sel == 0) ? q : k;
    // phase 1: acc -> Ts (wave-private rows; no barrier needed)
    #pragma unroll
    for (int ni = 0; ni < 4; ++ni) {
      const int o = nt * 64 + ni * 16 + l16;
      const float bs = bias[o];
      const int oc = ni * 16 + l16;
      #pragma unroll
      for (int mi = 0; mi < 2; ++mi) {
        const int nl = wv * 32 + mi * 16 + quad * 4;
        #pragma unroll
        for (int r = 0; r < 4; ++r)
          Ts[(nl + r) * 72 + oc] = f2bf((acc[mi][ni][r] + bs) * sc);
      }
    }
    // phase 2: coalesced 64B-run stores (same wave reads its own rows)
    const int n2 = tid >> 1;                 // 0..127
    const int hh = tid & 1;                  // head-half within the 64-col tile
    const int head = 2 * (nt & 3) + hh;
    const int g = mt * 128 + n2;
    const int bb = g >> 12, n0g = g & 4095;
    unsigned short* dst = base + ((size_t)(bb * NH + head) * NSEQ + n0g) * HD;
    #pragma unroll
    for (int j = 0; j < 4; ++j) {
      const uint4 v = *reinterpret_cast<const uint4*>(&Ts[n2 * 72 + hh * 32 + j * 8]);
      *reinterpret_cast<uint4*>(dst + j * 8) = v;
    }
  }
}

// ---------------- proj GEMM + residual (tiled, pipelined) ----------------
__global__ __launch_bounds__(256, 3) void proj_gemm(const unsigned short* __restrict__ xa,
                                                    const unsigned short* __restrict__ w,
                                                    const float* __restrict__ bias,
                                                    const float* __restrict__ gamma,
                                                    const float* __restrict__ x,
                                                    float* __restrict__ out) {
  __shared__ __align__(16) unsigned short Pool[24576];
  const int tid = threadIdx.x;
  const int wv  = tid >> 6;
  const int lane = tid & 63;
  const int quad = lane >> 4, l16 = lane & 15;
  const int mt = blockIdx.x;
  const int nt = blockIdx.y;

  f4x acc[2][4];
  #pragma unroll
  for (int mi = 0; mi < 2; ++mi)
    #pragma unroll
    for (int ni = 0; ni < 4; ++ni)
      acc[mi][ni] = (f4x){0.f, 0.f, 0.f, 0.f};

  GEMM_CORE2(xa, w, acc)

  const float g0 = gamma[0];
  #pragma unroll
  for (int ni = 0; ni < 4; ++ni) {
    const int c = nt * 64 + ni * 16 + l16;
    const float bs = bias[c];
    #pragma unroll
    for (int mi = 0; mi < 2; ++mi) {
      const int gr = mt * 128 + wv * 32 + mi * 16 + quad * 4;
      const int bb = gr >> 12, n0 = gr & 4095;
      const size_t off = (size_t)(bb * CCH + c) * NSEQ + n0;
      const float4 xv = *reinterpret_cast<const float4*>(x + off);
      float4 ov;
      ov.x = g0 * (acc[mi][ni][0] + bs) + xv.x;
      ov.y = g0 * (acc[mi][ni][1] + bs) + xv.y;
      ov.z = g0 * (acc[mi][ni][2] + bs) + xv.z;
      ov.w = g0 * (acc[mi][ni][3] + bs) + xv.w;
      *reinterpret_cast<float4*>(out + off) = ov;
    }
  }
}

// ---------------- Flash attention, split-KV + shared LDS K/V staging (R5, verbatim) ----------------
// Proven 65.5-67.6us. Do not touch: per-wave register K/V prefetch collapsed
// three times (R2/R4/R6); this LDS-staged loop-carried structure is the winner.
__global__ __launch_bounds__(256, 4) void fa_kernel(const unsigned short* __restrict__ q,
                                                    const unsigned short* __restrict__ k,
                                                    const unsigned short* __restrict__ vt,
                                                    float* __restrict__ Opart,
                                                    float* __restrict__ Lpart) {
  __shared__ unsigned short Ks[2][64 * 40];   // 2 x 5.0 KiB, kv-rows padded to 40 shorts
  __shared__ unsigned short Vs[2][32 * 72];   // 2 x 4.5 KiB, d-rows padded to 72 shorts
  __shared__ unsigned short Ps[128 * 72];     // 18 KiB, q-rows padded to 72 shorts

  const int tid  = threadIdx.x;
  const int wv   = tid >> 6;
  const int lane = tid & 63;
  const int quad = lane >> 4;
  const int l16  = lane & 15;
  const int i    = blockIdx.x;
  const int bh   = i & 15;          // XCD pinning
  const int rest = i >> 4;          // 0..63
  const int half = rest & 1;
  const int qblk = rest >> 1;       // 0..31
  const int kv0  = half * 2048;     // this block's KV range: [kv0, kv0+2048)

  const unsigned short* kb_ = k  + ((size_t)bh * NSEQ + kv0) * HD;
  const unsigned short* vb_ = vt + (size_t)bh * HD * NSEQ + kv0;

  // cooperative staging assignment (256 threads, 16B each)
  const int krow = tid >> 2;          // 0..63  kv row of K tile
  const int kdc  = (tid & 3) * 8;     // d col (shorts)
  const int vrow = tid >> 3;          // 0..31  d row of V^T tile
  const int vkc  = (tid & 7) * 8;     // kv col (shorts)

  s8x bq0, bq1;
  {
    const unsigned short* qb = q + ((size_t)bh * NSEQ + (size_t)qblk * 128 + wv * 32) * HD;
    bq0 = *reinterpret_cast<const s8x*>(qb + (size_t)l16 * HD + quad * 8);
    bq1 = *reinterpret_cast<const s8x*>(qb + (size_t)(16 + l16) * HD + quad * 8);
  }

  // prologue: stage tile 0, then issue loads for tile 1
  uint4 kreg = *reinterpret_cast<const uint4*>(kb_ + (size_t)krow * HD + kdc);
  uint4 vreg = *reinterpret_cast<const uint4*>(vb_ + (size_t)vrow * NSEQ + vkc);
  *reinterpret_cast<uint4*>(&Ks[0][krow * 40 + kdc]) = kreg;
  *reinterpret_cast<uint4*>(&Vs[0][vrow * 72 + vkc]) = vreg;
  kreg = *reinterpret_cast<const uint4*>(kb_ + (size_t)(64 + krow) * HD + kdc);
  vreg = *reinterpret_cast<const uint4*>(vb_ + (size_t)vrow * NSEQ + 64 + vkc);
  __syncthreads();

  // S(0) from Ks[0]
  f4x st[4][2];
  #pragma unroll
  for (int ii = 0; ii < 4; ++ii) {
    const s8x ak = *reinterpret_cast<const s8x*>(&Ks[0][(ii * 16 + l16) * 40 + quad * 8]);
    const f4x z = {0.f, 0.f, 0.f, 0.f};
    st[ii][0] = mfma16(ak, bq0, z);
    st[ii][1] = mfma16(ak, bq1, z);
  }

  f4x oacc[2][2];
  #pragma unroll
  for (int dt = 0; dt < 2; ++dt)
    #pragma unroll
    for (int ct = 0; ct < 2; ++ct)
      oacc[dt][ct] = (f4x){0.f, 0.f, 0.f, 0.f};
  f4x accL[2] = {(f4x){0.f, 0.f, 0.f, 0.f}, (f4x){0.f, 0.f, 0.f, 0.f}};

  s8x ones;
  #pragma unroll
  for (int j = 0; j < 8; ++j) ones[j] = (short)0x3F80;   // bf16 1.0

  const int r0 = (wv * 32 + l16) * 72;
  const int r1 = (wv * 32 + 16 + l16) * 72;

  for (int t = 0; t < 32; ++t) {
    const int c = t & 1;

    // ---- write staged tile t+1 into the back buffer (vmcnt wait is ~1 iter old) ----
    if (t + 1 < 32) {
      *reinterpret_cast<uint4*>(&Ks[c ^ 1][krow * 40 + kdc]) = kreg;
      *reinterpret_cast<uint4*>(&Vs[c ^ 1][vrow * 72 + vkc]) = vreg;
    }

    // ---- exp + pack + write P(t): VALU/trans + LDS-write stream ----
    #pragma unroll
    for (int ct = 0; ct < 2; ++ct) {
      const int prow = (wv * 32 + ct * 16 + l16) * 72;
      #pragma unroll
      for (int ii = 0; ii < 4; ++ii) {
        const float e0 = FEXP2(st[ii][ct][0]);
        const float e1 = FEXP2(st[ii][ct][1]);
        const float e2 = FEXP2(st[ii][ct][2]);
        const float e3 = FEXP2(st[ii][ct][3]);
        uint2 pw;
        pw.x = pk_bf_trunc(e0, e1);
        pw.y = pk_bf_trunc(e2, e3);
        *reinterpret_cast<uint2*>(&Ps[prow + ii * 16 + quad * 4]) = pw;
      }
    }

    // ---- issue global loads for tile t+2 (loop-carried: cannot be sunk) ----
    if (t + 2 < 32) {
      kreg = *reinterpret_cast<const uint4*>(kb_ + (size_t)((t + 2) * 64 + krow) * HD + kdc);
      vreg = *reinterpret_cast<const uint4*>(vb_ + (size_t)vrow * NSEQ + (t + 2) * 64 + vkc);
    }

    // ---- PV(t): read P + V from front buffer; MFMA streams ----
    #pragma unroll
    for (int kb2 = 0; kb2 < 2; ++kb2) {
      const s8x bp0 = *reinterpret_cast<const s8x*>(&Ps[r0 + kb2 * 32 + quad * 8]);
      const s8x bp1 = *reinterpret_cast<const s8x*>(&Ps[r1 + kb2 * 32 + quad * 8]);
      const s8x av0 = *reinterpret_cast<const s8x*>(&Vs[c][l16 * 72 + kb2 * 32 + quad * 8]);
      const s8x av1 = *reinterpret_cast<const s8x*>(&Vs[c][(16 + l16) * 72 + kb2 * 32 + quad * 8]);
      oacc[0][0] = mfma16(av0, bp0, oacc[0][0]);
      oacc[1][0] = mfma16(av1, bp0, oacc[1][0]);
      oacc[0][1] = mfma16(av0, bp1, oacc[0][1]);
      oacc[1][1] = mfma16(av1, bp1, oacc[1][1]);
      accL[0] = mfma16(ones, bp0, accL[0]);
      accL[1] = mfma16(ones, bp1, accL[1]);
    }

    __syncthreads();   // back buffer fully written; front buffer fully read

    // ---- S(t+1) from the freshly staged buffer ----
    if (t + 1 < 32) {
      #pragma unroll
      for (int ii = 0; ii < 4; ++ii) {
        const s8x ak = *reinterpret_cast<const s8x*>(&Ks[c ^ 1][(ii * 16 + l16) * 40 + quad * 8]);
        const f4x z = {0.f, 0.f, 0.f, 0.f};
        st[ii][0] = mfma16(ak, bq0, z);
        st[ii][1] = mfma16(ak, bq1, z);
      }
    }
  }

  // ---- epilogue: store partial O (f32) and partial l ----
  #pragma unroll
  for (int ct = 0; ct < 2; ++ct) {
    const int qg = qblk * 128 + wv * 32 + ct * 16 + l16;
    float* obase = Opart + ((size_t)(half * 16 + bh) * NSEQ + qg) * HD;
    #pragma unroll
    for (int dt = 0; dt < 2; ++dt) {
      float4 ov;
      ov.x = oacc[dt][ct][0]; ov.y = oacc[dt][ct][1];
      ov.z = oacc[dt][ct][2]; ov.w = oacc[dt][ct][3];
      *reinterpret_cast<float4*>(obase + dt * 16 + quad * 4) = ov;
    }
    if (quad == 0)
      Lpart[(size_t)(half * 16 + bh) * NSEQ + qg] = accL[ct][0];
  }
}

// ---------------- combine the two KV-halves: O=(O0+O1)/(l0+l1), write bf16 xa ----------------
__global__ __launch_bounds__(256) void fa_combine(const float* __restrict__ Opart,
                                                  const float* __restrict__ Lpart,
                                                  unsigned short* __restrict__ xa) {
  const int t  = blockIdx.x * 256 + threadIdx.x;   // 0..262143
  const int c8 = t & 3;                            // col group of 8
  const int n  = (t >> 2) & 4095;
  const int bh = t >> 14;
  const int b  = bh >> 3, h = bh & 7;

  const size_t o0 = ((size_t)bh * NSEQ + n) * HD + c8 * 8;
  const size_t o1 = o0 + (size_t)16 * NSEQ * HD;
  const float4 a0 = *reinterpret_cast<const float4*>(Opart + o0);
  const float4 a1 = *reinterpret_cast<const float4*>(Opart + o0 + 4);
  const float4 b0 = *reinterpret_cast<const float4*>(Opart + o1);
  const float4 b1 = *reinterpret_cast<const float4*>(Opart + o1 + 4);
  const float l0 = Lpart[(size_t)bh * NSEQ + n];
  const float l1 = Lpart[(size_t)(16 + bh) * NSEQ + n];
  const float rl = 1.f / (l0 + l1);

  uint4 ow;
  ow.x = pk_bf_rnd((a0.x + b0.x) * rl, (a0.y + b0.y) * rl);
  ow.y = pk_bf_rnd((a0.z + b0.z) * rl, (a0.w + b0.w) * rl);
  ow.z = pk_bf_rnd((a1.x + b1.x) * rl, (a1.y + b1.y) * rl);
  ow.w = pk_bf_rnd((a1.z + b1.z) * rl, (a1.w + b1.w) * rl);
  *reinterpret_cast<uint4*>(xa + ((size_t)b * NSEQ + n) * CCH + h * HD + c8 * 8) = ow;
}

extern "C" void kernel_launch(void* const* d_in, const int* in_sizes, int n_in,
                              void* d_out, int out_size, void* d_ws, size_t ws_size,
                              hipStream_t stream) {
  const float* x      = (const float*)d_in[0];
  const float* norm_w = (const float*)d_in[1];
  const float* norm_b = (const float*)d_in[2];
  const float* qkv_w  = (const float*)d_in[3];
  const float* qkv_b  = (const float*)d_in[4];
  const float* proj_w = (const float*)d_in[5];
  const float* proj_b = (const float*)d_in[6];
  const float* gamma  = (const float*)d_in[7];
  float* out = (float*)d_out;

  char* ws = (char*)d_ws;
  unsigned short* xn  = (unsigned short*)(ws);              // (B,N,C) bf16, 4 MiB
  unsigned short* qwb = (unsigned short*)(ws + 4194304);
  unsigned short* pwb = (unsigned short*)(ws + 4587520);
  unsigned short* q   = (unsigned short*)(ws + 4718592);    // (B,NH,N,HD), pre-scaled
  unsigned short* k   = (unsigned short*)(ws + 8912896);    // (B,NH,N,HD)
  unsigned short* vt  = (unsigned short*)(ws + 13107200);   // (B,NH,HD,N)
  unsigned short* xa  = (unsigned short*)(ws + 17301504);   // (B,N,C) bf16, 4 MiB
  float* Opart        = (float*)(ws + 21495808);            // [2][16][N][HD] f32, 16 MiB
  float* Lpart        = (float*)(ws + 38273024);            // [2][16][N] f32, 512 KiB

  hipLaunchKernelGGL(ln_cvt_kernel, dim3(512), dim3(256), 0, stream,
                     x, norm_w, norm_b, xn, qkv_w, proj_w, qwb, pwb);
  hipLaunchKernelGGL(qkv_gemm,  dim3(64, 12), dim3(256), 0, stream, xn, qwb, qkv_b, q, k, vt);
  hipLaunchKernelGGL(fa_kernel, dim3(1024), dim3(256), 0, stream, q, k, vt, Opart, Lpart);
  hipLaunchKernelGGL(fa_combine, dim3(1024), dim3(256), 0, stream, Opart, Lpart, xa);
  hipLaunchKernelGGL(proj_gemm, dim3(64, 4), dim3(256), 0, stream, xa, pwb, proj_b, gamma, x, out);
}

// Round 9
// 149.396 us; speedup vs baseline: 1.1596x; 1.1596x over previous
//
#include <hip/hip_runtime.h>

#define CCH   256
#define NSEQ  4096
#define NH    8
#define HD    32

typedef short s8x __attribute__((ext_vector_type(8)));
typedef float f4x __attribute__((ext_vector_type(4)));

__device__ __forceinline__ f4x mfma16(s8x a, s8x b, f4x c) {
  return __builtin_amdgcn_mfma_f32_16x16x32_bf16(a, b, c, 0, 0, 0);
}

__device__ __forceinline__ unsigned short f2bf(float f) {
  union { float f; unsigned int u; } v; v.f = f;
  unsigned int u = v.u + 0x7fffu + ((v.u >> 16) & 1u);
  return (unsigned short)(u >> 16);
}

__device__ __forceinline__ unsigned int pk_bf_rnd(float lo, float hi) {
  return (unsigned int)f2bf(lo) | ((unsigned int)f2bf(hi) << 16);
}

// pack two f32 -> one u32 of bf16 (truncating; P >= 0 so safe)
__device__ __forceinline__ unsigned int pk_bf_trunc(float lo, float hi) {
  union { float f; unsigned int u; } a, b; a.f = lo; b.f = hi;
  return __builtin_amdgcn_perm(b.u, a.u, 0x07060302);
}

// raw v_exp_f32
#if defined(__has_builtin)
#if __has_builtin(__builtin_amdgcn_exp2f)
#define FEXP2(x) __builtin_amdgcn_exp2f(x)
#endif
#endif
#ifndef FEXP2
__device__ __forceinline__ float __fexp2_asm(float x) {
  float r; asm("v_exp_f32 %0, %1" : "=v"(r) : "v"(x)); return r;
}
#define FEXP2(x) __fexp2_asm(x)
#endif

#define C2SCALE (0.17677669529663689f * 1.4426950408889634f)

// ---------------- LayerNorm + transpose, with cvt_weights folded in ----------------
// blocks 0..255: ln (32 positions each); blocks 256..511: weight fp32->bf16.
__global__ __launch_bounds__(256) void ln_cvt_kernel(const float* __restrict__ x,
                                                     const float* __restrict__ nw,
                                                     const float* __restrict__ nb,
                                                     unsigned short* __restrict__ xn,
                                                     const float* __restrict__ qw,
                                                     const float* __restrict__ pw,
                                                     unsigned short* __restrict__ qwb,
                                                     unsigned short* __restrict__ pwb) {
  if (blockIdx.x >= 256) {
    const int t = (blockIdx.x - 256) * 256 + threadIdx.x;   // 0..65535
    const float4* src;
    unsigned short* dst;
    int idx;
    if (t < 49152) { src = reinterpret_cast<const float4*>(qw); dst = qwb; idx = t; }
    else           { src = reinterpret_cast<const float4*>(pw); dst = pwb; idx = t - 49152; }
    const float4 vv = src[idx];
    union { unsigned short u[4]; uint2 v; } pk;
    pk.u[0] = f2bf(vv.x); pk.u[1] = f2bf(vv.y); pk.u[2] = f2bf(vv.z); pk.u[3] = f2bf(vv.w);
    *reinterpret_cast<uint2*>(dst + 4 * idx) = pk.v;
    return;
  }

  __shared__ float Ls[256 * 32];
  __shared__ float Sred[2][32][8];
  __shared__ float Mrs[32][2];
  const int t  = threadIdx.x;
  const int n  = t & 31;
  const int cg = t >> 5;
  const int p0 = blockIdx.x * 32;
  const int b  = p0 >> 12;
  const int n0 = p0 & 4095;
  const float* xb = x + (size_t)b * CCH * NSEQ + n0;

  #pragma unroll
  for (int i = 0; i < 32; ++i) {
    const int c = i * 8 + cg;
    Ls[c * 32 + (n ^ (c & 31))] = xb[(size_t)c * NSEQ + n];
  }
  __syncthreads();

  float s = 0.f, sq = 0.f;
  #pragma unroll
  for (int j = 0; j < 32; ++j) {
    const int c = cg * 32 + j;
    const float v = Ls[c * 32 + (n ^ j)];
    s += v; sq += v * v;
  }
  Sred[0][n][cg] = s; Sred[1][n][cg] = sq;
  __syncthreads();
  float ts = 0.f, tq = 0.f;
  #pragma unroll
  for (int g = 0; g < 8; ++g) { ts += Sred[0][n][g]; tq += Sred[1][n][g]; }
  const float mean = ts * (1.f / 256.f);
  const float rstd = rsqrtf(tq * (1.f / 256.f) - mean * mean + 1e-5f);
  if (cg == 0) { Mrs[n][0] = mean; Mrs[n][1] = rstd; }
  __syncthreads();

  // coalesced write phase: thread -> (row n2, col-block c8b)
  const int n2  = t >> 3;        // 0..31
  const int c8b = t & 7;
  const float mean2 = Mrs[n2][0];
  const float rstd2 = Mrs[n2][1];
  unsigned short* orow = xn + ((size_t)b * NSEQ + n0 + n2) * CCH;
  #pragma unroll
  for (int j8 = 0; j8 < 4; ++j8) {
    const int cb = (j8 * 8 + c8b) * 8;        // 0..248, step 8
    unsigned int w_[4];
    #pragma unroll
    for (int hw = 0; hw < 4; ++hw) {
      const int c = cb + hw * 2;
      const float v0 = Ls[c * 32 + (n2 ^ (c & 31))];
      const float v1 = Ls[(c + 1) * 32 + (n2 ^ ((c + 1) & 31))];
      const float y0 = (v0 - mean2) * rstd2 * nw[c] + nb[c];
      const float y1 = (v1 - mean2) * rstd2 * nw[c + 1] + nb[c + 1];
      w_[hw] = pk_bf_rnd(y0, y1);
    }
    uint4 pkv; pkv.x = w_[0]; pkv.y = w_[1]; pkv.z = w_[2]; pkv.w = w_[3];
    *reinterpret_cast<uint4*>(orow + cb) = pkv;
  }
}

// ======== shared LDS-tiled GEMM core: 128m x 64n tile, BK=64, K=256 ========
// R9: reverted to the R7/R0 2-barrier core. R8's 2-deep pipelined variant
// regressed +18us: 4 K-steps are too shallow to amortize the prologue, and
// 24 loop-carried VGPRs broke the compiler's batched load->ds_write schedule.
#define GEMM_CORE(A_PTR, B_PTR, ACC)                                            \
  {                                                                             \
    for (int kb = 0; kb < 4; ++kb) {                                            \
      if (kb) __syncthreads();                                                  \
      _Pragma("unroll")                                                         \
      for (int j = 0; j < 4; ++j) {                                             \
        const int c = j * 256 + tid;                                            \
        const int ar = c >> 3, acr = c & 7;                                     \
        *reinterpret_cast<s8x*>(&As[ar * 64 + ((acr ^ (ar & 7)) << 3)]) =       \
          *reinterpret_cast<const s8x*>(A_PTR + (size_t)(mt * 128 + ar) * CCH + kb * 64 + acr * 8); \
      }                                                                         \
      _Pragma("unroll")                                                         \
      for (int j = 0; j < 2; ++j) {                                             \
        const int c = j * 256 + tid;                                            \
        const int br = c >> 3, bcr = c & 7;                                     \
        *reinterpret_cast<s8x*>(&Bs[br * 64 + ((bcr ^ (br & 7)) << 3)]) =       \
          *reinterpret_cast<const s8x*>(B_PTR + (size_t)(nt * 64 + br) * CCH + kb * 64 + bcr * 8); \
      }                                                                         \
      __syncthreads();                                                          \
      _Pragma("unroll")                                                         \
      for (int kin = 0; kin < 2; ++kin) {                                       \
        const int chx = ((kin * 4 + quad) ^ (l16 & 7)) << 3;                    \
        const s8x a0 = *reinterpret_cast<const s8x*>(&As[(wv * 32 + l16) * 64 + chx]);      \
        const s8x a1 = *reinterpret_cast<const s8x*>(&As[(wv * 32 + 16 + l16) * 64 + chx]); \
        _Pragma("unroll")                                                       \
        for (int ni = 0; ni < 4; ++ni) {                                        \
          const s8x bf = *reinterpret_cast<const s8x*>(&Bs[(ni * 16 + l16) * 64 + chx]);    \
          ACC[0][ni] = mfma16(a0, bf, ACC[0][ni]);                              \
          ACC[1][ni] = mfma16(a1, bf, ACC[1][ni]);                              \
        }                                                                       \
      }                                                                         \
    }                                                                           \
  }

// ---------------- QKV GEMM (tiled) ----------------
__global__ __launch_bounds__(256, 3) void qkv_gemm(const unsigned short* __restrict__ xn,
                                                   const unsigned short* __restrict__ w,
                                                   const float* __restrict__ bias,
                                                   unsigned short* __restrict__ q,
                                                   unsigned short* __restrict__ k,
                                                   unsigned short* __restrict__ vt) {
  __shared__ unsigned short As[128 * 64];
  __shared__ unsigned short Bs[64 * 64];
  __shared__ unsigned short Ts[128 * 72];
  const int tid = threadIdx.x;
  const int wv  = tid >> 6;
  const int lane = tid & 63;
  const int quad = lane >> 4, l16 = lane & 15;
  const int mt = blockIdx.x;
  const int nt = blockIdx.y;

  f4x acc[2][4];
  #pragma unroll
  for (int mi = 0; mi < 2; ++mi)
    #pragma unroll
    for (int ni = 0; ni < 4; ++ni)
      acc[mi][ni] = (f4x){0.f, 0.f, 0.f, 0.f};

  GEMM_CORE(xn, w, acc)

  const int sel = nt >> 2;                  // wave-uniform: 0=q 1=k 2=v
  if (sel == 2) {
    #pragma unroll
    for (int ni = 0; ni < 4; ++ni) {
      const int o = nt * 64 + ni * 16 + l16;
      const float bs = bias[o];
      const int ol = o & 255;
      const int head = ol >> 5, d = ol & 31;
      #pragma unroll
      for (int mi = 0; mi < 2; ++mi) {
        const int g0 = mt * 128 + wv * 32 + mi * 16 + quad * 4;
        const int bb = g0 >> 12, n0 = g0 & 4095;
        unsigned short* vp = vt + ((size_t)(bb * NH + head) * HD + d) * NSEQ + n0;
        uint2 pk;
        pk.x = pk_bf_rnd(acc[mi][ni][0] + bs, acc[mi][ni][1] + bs);
        pk.y = pk_bf_rnd(acc[mi][ni][2] + bs, acc[mi][ni][3] + bs);
        *reinterpret_cast<uint2*>(vp) = pk;
      }
    }
  } else {
    const float sc = (sel == 0) ? C2SCALE : 1.f;
    unsigned short* base = (sel == 0) ? q : k;
    // phase 1: acc -> Ts (wave-private rows; no barrier needed)
    #pragma unroll
    for (int ni = 0; ni < 4; ++ni) {
      const int o = nt * 64 + ni * 16 + l16;
      const float bs = bias[o];
      const int oc = ni * 16 + l16;
      #pragma unroll
      for (int mi = 0; mi < 2; ++mi) {
        const int nl = wv * 32 + mi * 16 + quad * 4;
        #pragma unroll
        for (int r = 0; r < 4; ++r)
          Ts[(nl + r) * 72 + oc] = f2bf((acc[mi][ni][r] + bs) * sc);
      }
    }
    // phase 2: coalesced 64B-run stores (same wave reads its own rows)
    const int n2 = tid >> 1;                 // 0..127
    const int hh = tid & 1;                  // head-half within the 64-col tile
    const int head = 2 * (nt & 3) + hh;
    const int g = mt * 128 + n2;
    const int bb = g >> 12, n0g = g & 4095;
    unsigned short* dst = base + ((size_t)(bb * NH + head) * NSEQ + n0g) * HD;
    #pragma unroll
    for (int j = 0; j < 4; ++j) {
      const uint4 v = *reinterpret_cast<const uint4*>(&Ts[n2 * 72 + hh * 32 + j * 8]);
      *reinterpret_cast<uint4*>(dst + j * 8) = v;
    }
  }
}

// ---------------- proj GEMM + residual (tiled) ----------------
__global__ __launch_bounds__(256, 3) void proj_gemm(const unsigned short* __restrict__ xa,
                                                    const unsigned short* __restrict__ w,
                                                    const float* __restrict__ bias,
                                                    const float* __restrict__ gamma,
                                                    const float* __restrict__ x,
                                                    float* __restrict__ out) {
  __shared__ unsigned short As[128 * 64];
  __shared__ unsigned short Bs[64 * 64];
  const int tid = threadIdx.x;
  const int wv  = tid >> 6;
  const int lane = tid & 63;
  const int quad = lane >> 4, l16 = lane & 15;
  const int mt = blockIdx.x;
  const int nt = blockIdx.y;

  f4x acc[2][4];
  #pragma unroll
  for (int mi = 0; mi < 2; ++mi)
    #pragma unroll
    for (int ni = 0; ni < 4; ++ni)
      acc[mi][ni] = (f4x){0.f, 0.f, 0.f, 0.f};

  GEMM_CORE(xa, w, acc)

  const float g0 = gamma[0];
  #pragma unroll
  for (int ni = 0; ni < 4; ++ni) {
    const int c = nt * 64 + ni * 16 + l16;
    const float bs = bias[c];
    #pragma unroll
    for (int mi = 0; mi < 2; ++mi) {
      const int gr = mt * 128 + wv * 32 + mi * 16 + quad * 4;
      const int bb = gr >> 12, n0 = gr & 4095;
      const size_t off = (size_t)(bb * CCH + c) * NSEQ + n0;
      const float4 xv = *reinterpret_cast<const float4*>(x + off);
      float4 ov;
      ov.x = g0 * (acc[mi][ni][0] + bs) + xv.x;
      ov.y = g0 * (acc[mi][ni][1] + bs) + xv.y;
      ov.z = g0 * (acc[mi][ni][2] + bs) + xv.z;
      ov.w = g0 * (acc[mi][ni][3] + bs) + xv.w;
      *reinterpret_cast<float4*>(out + off) = ov;
    }
  }
}

// ---------------- Flash attention: R5 staging + PV-lag (R9) ----------------
// R5 base (LDS K/V dbuf, loop-carried reg staging, 1 barrier/iter) proven 65.5us.
// R9 adds PV-lag WITHOUT the R6 register-prefetch failure:
//  - P rows are wave-private and LDS ops complete in-order per wave, so PV(t-1)'s
//    P-reads issue at the TOP of iter t, before exp(t) overwrites the single Ps
//    buffer (read-before-write in program order = safe, no P double-buffer).
//  - V(t-1) for the lagged PV is carried in 4 s8x regs (vavr), loaded from the
//    FRONT V buffer at the end of iter t-1 (race-free slot, same place R5 read it).
// Iter order: [A: P(t-1) reads] [B: K/V back-writes] [D: PV(t-1) MFMAs]
//             [C+E: exp(t)+pack+P(t) writes] [F: t+2 loads] [G: V(t)->vavr]
//             [barrier] [I: S(t+1)].  exp overlaps the PV MFMA stream; the
// P write->read round-trip leaves the serial chain. Numerics bit-identical.
__global__ __launch_bounds__(256, 4) void fa_kernel(const unsigned short* __restrict__ q,
                                                    const unsigned short* __restrict__ k,
                                                    const unsigned short* __restrict__ vt,
                                                    float* __restrict__ Opart,
                                                    float* __restrict__ Lpart) {
  __shared__ unsigned short Ks[2][64 * 40];   // 2 x 5.0 KiB, kv-rows padded to 40 shorts
  __shared__ unsigned short Vs[2][32 * 72];   // 2 x 4.5 KiB, d-rows padded to 72 shorts
  __shared__ unsigned short Ps[128 * 72];     // 18 KiB, q-rows padded to 72 shorts

  const int tid  = threadIdx.x;
  const int wv   = tid >> 6;
  const int lane = tid & 63;
  const int quad = lane >> 4;
  const int l16  = lane & 15;
  const int i    = blockIdx.x;
  const int bh   = i & 15;          // XCD pinning
  const int rest = i >> 4;          // 0..63
  const int half = rest & 1;
  const int qblk = rest >> 1;       // 0..31
  const int kv0  = half * 2048;     // this block's KV range: [kv0, kv0+2048)

  const unsigned short* kb_ = k  + ((size_t)bh * NSEQ + kv0) * HD;
  const unsigned short* vb_ = vt + (size_t)bh * HD * NSEQ + kv0;

  // cooperative staging assignment (256 threads, 16B each)
  const int krow = tid >> 2;          // 0..63  kv row of K tile
  const int kdc  = (tid & 3) * 8;     // d col (shorts)
  const int vrow = tid >> 3;          // 0..31  d row of V^T tile
  const int vkc  = (tid & 7) * 8;     // kv col (shorts)

  s8x bq0, bq1;
  {
    const unsigned short* qb = q + ((size_t)bh * NSEQ + (size_t)qblk * 128 + wv * 32) * HD;
    bq0 = *reinterpret_cast<const s8x*>(qb + (size_t)l16 * HD + quad * 8);
    bq1 = *reinterpret_cast<const s8x*>(qb + (size_t)(16 + l16) * HD + quad * 8);
  }

  // prologue: stage tile 0, then issue loads for tile 1
  uint4 kreg = *reinterpret_cast<const uint4*>(kb_ + (size_t)krow * HD + kdc);
  uint4 vreg = *reinterpret_cast<const uint4*>(vb_ + (size_t)vrow * NSEQ + vkc);
  *reinterpret_cast<uint4*>(&Ks[0][krow * 40 + kdc]) = kreg;
  *reinterpret_cast<uint4*>(&Vs[0][vrow * 72 + vkc]) = vreg;
  kreg = *reinterpret_cast<const uint4*>(kb_ + (size_t)(64 + krow) * HD + kdc);
  vreg = *reinterpret_cast<const uint4*>(vb_ + (size_t)vrow * NSEQ + 64 + vkc);
  __syncthreads();

  // S(0) from Ks[0]
  f4x st[4][2];
  #pragma unroll
  for (int ii = 0; ii < 4; ++ii) {
    const s8x ak = *reinterpret_cast<const s8x*>(&Ks[0][(ii * 16 + l16) * 40 + quad * 8]);
    const f4x z = {0.f, 0.f, 0.f, 0.f};
    st[ii][0] = mfma16(ak, bq0, z);
    st[ii][1] = mfma16(ak, bq1, z);
  }

  f4x oacc[2][2];
  #pragma unroll
  for (int dt = 0; dt < 2; ++dt)
    #pragma unroll
    for (int ct = 0; ct < 2; ++ct)
      oacc[dt][ct] = (f4x){0.f, 0.f, 0.f, 0.f};
  f4x accL[2] = {(f4x){0.f, 0.f, 0.f, 0.f}, (f4x){0.f, 0.f, 0.f, 0.f}};

  s8x ones;
  #pragma unroll
  for (int j = 0; j < 8; ++j) ones[j] = (short)0x3F80;   // bf16 1.0

  const int r0 = (wv * 32 + l16) * 72;
  const int r1 = (wv * 32 + 16 + l16) * 72;

  s8x vavr[4];   // V(t) fragments carried in regs for next iter's lagged PV

  for (int t = 0; t < 32; ++t) {
    const int c = t & 1;

    // ---- A: read P(t-1) fragments (MUST precede this iter's P writes; in-order LDS) ----
    s8x bp[4];
    if (t > 0) {
      bp[0] = *reinterpret_cast<const s8x*>(&Ps[r0 + 0 * 32 + quad * 8]);
      bp[1] = *reinterpret_cast<const s8x*>(&Ps[r1 + 0 * 32 + quad * 8]);
      bp[2] = *reinterpret_cast<const s8x*>(&Ps[r0 + 1 * 32 + quad * 8]);
      bp[3] = *reinterpret_cast<const s8x*>(&Ps[r1 + 1 * 32 + quad * 8]);
    }

    // ---- B: write staged tile t+1 into the back buffers ----
    if (t + 1 < 32) {
      *reinterpret_cast<uint4*>(&Ks[c ^ 1][krow * 40 + kdc]) = kreg;
      *reinterpret_cast<uint4*>(&Vs[c ^ 1][vrow * 72 + vkc]) = vreg;
    }

    // ---- D: PV(t-1) MFMAs (independent of exp below; overlaps on MFMA pipe) ----
    if (t > 0) {
      #pragma unroll
      for (int kb2 = 0; kb2 < 2; ++kb2) {
        oacc[0][0] = mfma16(vavr[kb2],     bp[2 * kb2],     oacc[0][0]);
        oacc[1][0] = mfma16(vavr[2 + kb2], bp[2 * kb2],     oacc[1][0]);
        oacc[0][1] = mfma16(vavr[kb2],     bp[2 * kb2 + 1], oacc[0][1]);
        oacc[1][1] = mfma16(vavr[2 + kb2], bp[2 * kb2 + 1], oacc[1][1]);
        accL[0] = mfma16(ones, bp[2 * kb2],     accL[0]);
        accL[1] = mfma16(ones, bp[2 * kb2 + 1], accL[1]);
      }
    }

    // ---- C+E: exp(t) + pack + write P(t) (after A in program order: safe) ----
    #pragma unroll
    for (int ct = 0; ct < 2; ++ct) {
      const int prow = (wv * 32 + ct * 16 + l16) * 72;
      #pragma unroll
      for (int ii = 0; ii < 4; ++ii) {
        const float e0 = FEXP2(st[ii][ct][0]);
        const float e1 = FEXP2(st[ii][ct][1]);
        const float e2 = FEXP2(st[ii][ct][2]);
        const float e3 = FEXP2(st[ii][ct][3]);
        uint2 pw;
        pw.x = pk_bf_trunc(e0, e1);
        pw.y = pk_bf_trunc(e2, e3);
        *reinterpret_cast<uint2*>(&Ps[prow + ii * 16 + quad * 4]) = pw;
      }
    }

    // ---- F: issue global loads for tile t+2 (loop-carried: cannot be sunk) ----
    if (t + 2 < 32) {
      kreg = *reinterpret_cast<const uint4*>(kb_ + (size_t)((t + 2) * 64 + krow) * HD + kdc);
      vreg = *reinterpret_cast<const uint4*>(vb_ + (size_t)vrow * NSEQ + (t + 2) * 64 + vkc);
    }

    // ---- G: V(t) fragments -> regs from FRONT buffer (race-free) ----
    #pragma unroll
    for (int kb2 = 0; kb2 < 2; ++kb2) {
      vavr[kb2]     = *reinterpret_cast<const s8x*>(&Vs[c][l16 * 72 + kb2 * 32 + quad * 8]);
      vavr[2 + kb2] = *reinterpret_cast<const s8x*>(&Vs[c][(16 + l16) * 72 + kb2 * 32 + quad * 8]);
    }

    __syncthreads();   // back buffers fully written; fronts fully read

    // ---- I: S(t+1) from the freshly staged K buffer ----
    if (t + 1 < 32) {
      #pragma unroll
      for (int ii = 0; ii < 4; ++ii) {
        const s8x ak = *reinterpret_cast<const s8x*>(&Ks[c ^ 1][(ii * 16 + l16) * 40 + quad * 8]);
        const f4x z = {0.f, 0.f, 0.f, 0.f};
        st[ii][0] = mfma16(ak, bq0, z);
        st[ii][1] = mfma16(ak, bq1, z);
      }
    }
  }

  // ---- epilogue: PV(31) (P(31) in Ps, V(31) in vavr) ----
  {
    s8x bp[4];
    bp[0] = *reinterpret_cast<const s8x*>(&Ps[r0 + 0 * 32 + quad * 8]);
    bp[1] = *reinterpret_cast<const s8x*>(&Ps[r1 + 0 * 32 + quad * 8]);
    bp[2] = *reinterpret_cast<const s8x*>(&Ps[r0 + 1 * 32 + quad * 8]);
    bp[3] = *reinterpret_cast<const s8x*>(&Ps[r1 + 1 * 32 + quad * 8]);
    #pragma unroll
    for (int kb2 = 0; kb2 < 2; ++kb2) {
      oacc[0][0] = mfma16(vavr[kb2],     bp[2 * kb2],     oacc[0][0]);
      oacc[1][0] = mfma16(vavr[2 + kb2], bp[2 * kb2],     oacc[1][0]);
      oacc[0][1] = mfma16(vavr[kb2],     bp[2 * kb2 + 1], oacc[0][1]);
      oacc[1][1] = mfma16(vavr[2 + kb2], bp[2 * kb2 + 1], oacc[1][1]);
      accL[0] = mfma16(ones, bp[2 * kb2],     accL[0]);
      accL[1] = mfma16(ones, bp[2 * kb2 + 1], accL[1]);
    }
  }

  // ---- epilogue: store partial O (f32) and partial l ----
  #pragma unroll
  for (int ct = 0; ct < 2; ++ct) {
    const int qg = qblk * 128 + wv * 32 + ct * 16 + l16;
    float* obase = Opart + ((size_t)(half * 16 + bh) * NSEQ + qg) * HD;
    #pragma unroll
    for (int dt = 0; dt < 2; ++dt) {
      float4 ov;
      ov.x = oacc[dt][ct][0]; ov.y = oacc[dt][ct][1];
      ov.z = oacc[dt][ct][2]; ov.w = oacc[dt][ct][3];
      *reinterpret_cast<float4*>(obase + dt * 16 + quad * 4) = ov;
    }
    if (quad == 0)
      Lpart[(size_t)(half * 16 + bh) * NSEQ + qg] = accL[ct][0];
  }
}

// ---------------- combine the two KV-halves: O=(O0+O1)/(l0+l1), write bf16 xa ----------------
__global__ __launch_bounds__(256) void fa_combine(const float* __restrict__ Opart,
                                                  const float* __restrict__ Lpart,
                                                  unsigned short* __restrict__ xa) {
  const int t  = blockIdx.x * 256 + threadIdx.x;   // 0..262143
  const int c8 = t & 3;                            // col group of 8
  const int n  = (t >> 2) & 4095;
  const int bh = t >> 14;
  const int b  = bh >> 3, h = bh & 7;

  const size_t o0 = ((size_t)bh * NSEQ + n) * HD + c8 * 8;
  const size_t o1 = o0 + (size_t)16 * NSEQ * HD;
  const float4 a0 = *reinterpret_cast<const float4*>(Opart + o0);
  const float4 a1 = *reinterpret_cast<const float4*>(Opart + o0 + 4);
  const float4 b0 = *reinterpret_cast<const float4*>(Opart + o1);
  const float4 b1 = *reinterpret_cast<const float4*>(Opart + o1 + 4);
  const float l0 = Lpart[(size_t)bh * NSEQ + n];
  const float l1 = Lpart[(size_t)(16 + bh) * NSEQ + n];
  const float rl = 1.f / (l0 + l1);

  uint4 ow;
  ow.x = pk_bf_rnd((a0.x + b0.x) * rl, (a0.y + b0.y) * rl);
  ow.y = pk_bf_rnd((a0.z + b0.z) * rl, (a0.w + b0.w) * rl);
  ow.z = pk_bf_rnd((a1.x + b1.x) * rl, (a1.y + b1.y) * rl);
  ow.w = pk_bf_rnd((a1.z + b1.z) * rl, (a1.w + b1.w) * rl);
  *reinterpret_cast<uint4*>(xa + ((size_t)b * NSEQ + n) * CCH + h * HD + c8 * 8) = ow;
}

extern "C" void kernel_launch(void* const* d_in, const int* in_sizes, int n_in,
                              void* d_out, int out_size, void* d_ws, size_t ws_size,
                              hipStream_t stream) {
  const float* x      = (const float*)d_in[0];
  const float* norm_w = (const float*)d_in[1];
  const float* norm_b = (const float*)d_in[2];
  const float* qkv_w  = (const float*)d_in[3];
  const float* qkv_b  = (const float*)d_in[4];
  const float* proj_w = (const float*)d_in[5];
  const float* proj_b = (const float*)d_in[6];
  const float* gamma  = (const float*)d_in[7];
  float* out = (float*)d_out;

  char* ws = (char*)d_ws;
  unsigned short* xn  = (unsigned short*)(ws);              // (B,N,C) bf16, 4 MiB
  unsigned short* qwb = (unsigned short*)(ws + 4194304);
  unsigned short* pwb = (unsigned short*)(ws + 4587520);
  unsigned short* q   = (unsigned short*)(ws + 4718592);    // (B,NH,N,HD), pre-scaled
  unsigned short* k   = (unsigned short*)(ws + 8912896);    // (B,NH,N,HD)
  unsigned short* vt  = (unsigned short*)(ws + 13107200);   // (B,NH,HD,N)
  unsigned short* xa  = (unsigned short*)(ws + 17301504);   // (B,N,C) bf16, 4 MiB
  float* Opart        = (float*)(ws + 21495808);            // [2][16][N][HD] f32, 16 MiB
  float* Lpart        = (float*)(ws + 38273024);            // [2][16][N] f32, 512 KiB

  hipLaunchKernelGGL(ln_cvt_kernel, dim3(512), dim3(256), 0, stream,
                     x, norm_w, norm_b, xn, qkv_w, proj_w, qwb, pwb);
  hipLaunchKernelGGL(qkv_gemm,  dim3(64, 12), dim3(256), 0, stream, xn, qwb, qkv_b, q, k, vt);
  hipLaunchKernelGGL(fa_kernel, dim3(1024), dim3(256), 0, stream, q, k, vt, Opart, Lpart);
  hipLaunchKernelGGL(fa_combine, dim3(1024), dim3(256), 0, stream, Opart, Lpart, xa);
  hipLaunchKernelGGL(proj_gemm, dim3(64, 4), dim3(256), 0, stream, xa, pwb, proj_b, gamma, x, out);
}

// Round 10
// 147.139 us; speedup vs baseline: 1.1774x; 1.0153x over previous
//
#include <hip/hip_runtime.h>

#define CCH   256
#define NSEQ  4096
#define NH    8
#define HD    32

typedef short s8x __attribute__((ext_vector_type(8)));
typedef float f4x __attribute__((ext_vector_type(4)));

__device__ __forceinline__ f4x mfma16(s8x a, s8x b, f4x c) {
  return __builtin_amdgcn_mfma_f32_16x16x32_bf16(a, b, c, 0, 0, 0);
}

__device__ __forceinline__ unsigned short f2bf(float f) {
  union { float f; unsigned int u; } v; v.f = f;
  unsigned int u = v.u + 0x7fffu + ((v.u >> 16) & 1u);
  return (unsigned short)(u >> 16);
}

__device__ __forceinline__ unsigned int pk_bf_rnd(float lo, float hi) {
  return (unsigned int)f2bf(lo) | ((unsigned int)f2bf(hi) << 16);
}

// pack two f32 -> one u32 of bf16 (truncating; P >= 0 so safe)
__device__ __forceinline__ unsigned int pk_bf_trunc(float lo, float hi) {
  union { float f; unsigned int u; } a, b; a.f = lo; b.f = hi;
  return __builtin_amdgcn_perm(b.u, a.u, 0x07060302);
}

// raw v_exp_f32
#if defined(__has_builtin)
#if __has_builtin(__builtin_amdgcn_exp2f)
#define FEXP2(x) __builtin_amdgcn_exp2f(x)
#endif
#endif
#ifndef FEXP2
__device__ __forceinline__ float __fexp2_asm(float x) {
  float r; asm("v_exp_f32 %0, %1" : "=v"(r) : "v"(x)); return r;
}
#define FEXP2(x) __fexp2_asm(x)
#endif

#define C2SCALE (0.17677669529663689f * 1.4426950408889634f)

// ---------------- LayerNorm + transpose, with cvt_weights folded in ----------------
__global__ __launch_bounds__(256) void ln_cvt_kernel(const float* __restrict__ x,
                                                     const float* __restrict__ nw,
                                                     const float* __restrict__ nb,
                                                     unsigned short* __restrict__ xn,
                                                     const float* __restrict__ qw,
                                                     const float* __restrict__ pw,
                                                     unsigned short* __restrict__ qwb,
                                                     unsigned short* __restrict__ pwb) {
  if (blockIdx.x >= 256) {
    const int t = (blockIdx.x - 256) * 256 + threadIdx.x;   // 0..65535
    const float4* src;
    unsigned short* dst;
    int idx;
    if (t < 49152) { src = reinterpret_cast<const float4*>(qw); dst = qwb; idx = t; }
    else           { src = reinterpret_cast<const float4*>(pw); dst = pwb; idx = t - 49152; }
    const float4 vv = src[idx];
    union { unsigned short u[4]; uint2 v; } pk;
    pk.u[0] = f2bf(vv.x); pk.u[1] = f2bf(vv.y); pk.u[2] = f2bf(vv.z); pk.u[3] = f2bf(vv.w);
    *reinterpret_cast<uint2*>(dst + 4 * idx) = pk.v;
    return;
  }

  __shared__ float Ls[256 * 32];
  __shared__ float Sred[2][32][8];
  __shared__ float Mrs[32][2];
  const int t  = threadIdx.x;
  const int n  = t & 31;
  const int cg = t >> 5;
  const int p0 = blockIdx.x * 32;
  const int b  = p0 >> 12;
  const int n0 = p0 & 4095;
  const float* xb = x + (size_t)b * CCH * NSEQ + n0;

  #pragma unroll
  for (int i = 0; i < 32; ++i) {
    const int c = i * 8 + cg;
    Ls[c * 32 + (n ^ (c & 31))] = xb[(size_t)c * NSEQ + n];
  }
  __syncthreads();

  float s = 0.f, sq = 0.f;
  #pragma unroll
  for (int j = 0; j < 32; ++j) {
    const int c = cg * 32 + j;
    const float v = Ls[c * 32 + (n ^ j)];
    s += v; sq += v * v;
  }
  Sred[0][n][cg] = s; Sred[1][n][cg] = sq;
  __syncthreads();
  float ts = 0.f, tq = 0.f;
  #pragma unroll
  for (int g = 0; g < 8; ++g) { ts += Sred[0][n][g]; tq += Sred[1][n][g]; }
  const float mean = ts * (1.f / 256.f);
  const float rstd = rsqrtf(tq * (1.f / 256.f) - mean * mean + 1e-5f);
  if (cg == 0) { Mrs[n][0] = mean; Mrs[n][1] = rstd; }
  __syncthreads();

  // coalesced write phase: thread -> (row n2, col-block c8b)
  const int n2  = t >> 3;        // 0..31
  const int c8b = t & 7;
  const float mean2 = Mrs[n2][0];
  const float rstd2 = Mrs[n2][1];
  unsigned short* orow = xn + ((size_t)b * NSEQ + n0 + n2) * CCH;
  #pragma unroll
  for (int j8 = 0; j8 < 4; ++j8) {
    const int cb = (j8 * 8 + c8b) * 8;        // 0..248, step 8
    unsigned int w_[4];
    #pragma unroll
    for (int hw = 0; hw < 4; ++hw) {
      const int c = cb + hw * 2;
      const float v0 = Ls[c * 32 + (n2 ^ (c & 31))];
      const float v1 = Ls[(c + 1) * 32 + (n2 ^ ((c + 1) & 31))];
      const float y0 = (v0 - mean2) * rstd2 * nw[c] + nb[c];
      const float y1 = (v1 - mean2) * rstd2 * nw[c + 1] + nb[c + 1];
      w_[hw] = pk_bf_rnd(y0, y1);
    }
    uint4 pkv; pkv.x = w_[0]; pkv.y = w_[1]; pkv.z = w_[2]; pkv.w = w_[3];
    *reinterpret_cast<uint4*>(orow + cb) = pkv;
  }
}

// ---------------- QKV GEMM: R10 64x64 tiles for occupancy ----------------
// R9 ledger: non-fa residue stuck at ~88us across 10 rounds while its traffic/
// compute roofline is ~25us. proj grid was 256 blocks = 1 block/CU (12.5% occ),
// qkv 768 = 3/CU. These staging loops are latency-bound (compute ~1-3us!) and
// need TLP. R10: same proven 2-barrier core, HALVED tile -> 2x grid.
// qkv: 64x64 tile, grid (128,12)=1536 blocks, LDS 16KB, launch_bounds(256,6)
// -> 6 blocks/CU = 24 waves/CU. Guard: VGPR must be <=85 (spill -> revert).
__global__ __launch_bounds__(256, 6) void qkv_gemm(const unsigned short* __restrict__ xn,
                                                   const unsigned short* __restrict__ w,
                                                   const float* __restrict__ bias,
                                                   unsigned short* __restrict__ q,
                                                   unsigned short* __restrict__ k,
                                                   unsigned short* __restrict__ vt) {
  __shared__ unsigned short As[64 * 64];
  __shared__ unsigned short Bs[64 * 64];
  const int tid = threadIdx.x;
  const int wv  = tid >> 6;
  const int lane = tid & 63;
  const int quad = lane >> 4, l16 = lane & 15;
  const int mt = blockIdx.x;   // 0..127
  const int nt = blockIdx.y;   // 0..11

  f4x acc[4];
  #pragma unroll
  for (int ni = 0; ni < 4; ++ni)
    acc[ni] = (f4x){0.f, 0.f, 0.f, 0.f};

  for (int kb = 0; kb < 4; ++kb) {
    if (kb) __syncthreads();
    #pragma unroll
    for (int j = 0; j < 2; ++j) {
      const int c = j * 256 + tid;
      const int ar = c >> 3, acr = c & 7;
      *reinterpret_cast<s8x*>(&As[ar * 64 + ((acr ^ (ar & 7)) << 3)]) =
        *reinterpret_cast<const s8x*>(xn + (size_t)(mt * 64 + ar) * CCH + kb * 64 + acr * 8);
    }
    #pragma unroll
    for (int j = 0; j < 2; ++j) {
      const int c = j * 256 + tid;
      const int br = c >> 3, bcr = c & 7;
      *reinterpret_cast<s8x*>(&Bs[br * 64 + ((bcr ^ (br & 7)) << 3)]) =
        *reinterpret_cast<const s8x*>(w + (size_t)(nt * 64 + br) * CCH + kb * 64 + bcr * 8);
    }
    __syncthreads();
    #pragma unroll
    for (int kin = 0; kin < 2; ++kin) {
      const int chx = ((kin * 4 + quad) ^ (l16 & 7)) << 3;
      const s8x a0 = *reinterpret_cast<const s8x*>(&As[(wv * 16 + l16) * 64 + chx]);
      #pragma unroll
      for (int ni = 0; ni < 4; ++ni) {
        const s8x bf = *reinterpret_cast<const s8x*>(&Bs[(ni * 16 + l16) * 64 + chx]);
        acc[ni] = mfma16(a0, bf, acc[ni]);
      }
    }
  }

  const int sel = nt >> 2;                  // wave-uniform: 0=q 1=k 2=v
  #pragma unroll
  for (int ni = 0; ni < 4; ++ni) {
    const int o = nt * 64 + ni * 16 + l16;
    const float bs = bias[o];
    const int ol = o & 255;
    const int head = ol >> 5, d = ol & 31;
    const int g0 = mt * 64 + wv * 16 + quad * 4;
    const int bb = g0 >> 12, n0 = g0 & 4095;
    if (sel == 2) {
      unsigned short* vp = vt + ((size_t)(bb * NH + head) * HD + d) * NSEQ + n0;
      uint2 pk;
      pk.x = pk_bf_rnd(acc[ni][0] + bs, acc[ni][1] + bs);
      pk.y = pk_bf_rnd(acc[ni][2] + bs, acc[ni][3] + bs);
      *reinterpret_cast<uint2*>(vp) = pk;
    } else {
      const float sc = (sel == 0) ? C2SCALE : 1.f;
      unsigned short* base = (sel == 0) ? q : k;
      #pragma unroll
      for (int r = 0; r < 4; ++r)
        base[((size_t)(bb * NH + head) * NSEQ + n0 + r) * HD + d] = f2bf((acc[ni][r] + bs) * sc);
    }
  }
}

// ---------------- proj GEMM + residual: R10 64x32 tiles for occupancy ----------------
// grid (128,8)=1024 blocks, LDS 12KB -> 4 blocks/CU = 16 waves/CU (was 1 block/CU!).
__global__ __launch_bounds__(256, 6) void proj_gemm(const unsigned short* __restrict__ xa,
                                                    const unsigned short* __restrict__ w,
                                                    const float* __restrict__ bias,
                                                    const float* __restrict__ gamma,
                                                    const float* __restrict__ x,
                                                    float* __restrict__ out) {
  __shared__ unsigned short As[64 * 64];
  __shared__ unsigned short Bs[32 * 64];
  const int tid = threadIdx.x;
  const int wv  = tid >> 6;
  const int lane = tid & 63;
  const int quad = lane >> 4, l16 = lane & 15;
  const int mt = blockIdx.x;   // 0..127
  const int nt = blockIdx.y;   // 0..7

  f4x acc[2];
  acc[0] = (f4x){0.f, 0.f, 0.f, 0.f};
  acc[1] = (f4x){0.f, 0.f, 0.f, 0.f};

  for (int kb = 0; kb < 4; ++kb) {
    if (kb) __syncthreads();
    #pragma unroll
    for (int j = 0; j < 2; ++j) {
      const int c = j * 256 + tid;
      const int ar = c >> 3, acr = c & 7;
      *reinterpret_cast<s8x*>(&As[ar * 64 + ((acr ^ (ar & 7)) << 3)]) =
        *reinterpret_cast<const s8x*>(xa + (size_t)(mt * 64 + ar) * CCH + kb * 64 + acr * 8);
    }
    {
      const int c = tid;                      // 32*64 shorts = exactly 1 s8x/thread
      const int br = c >> 3, bcr = c & 7;
      *reinterpret_cast<s8x*>(&Bs[br * 64 + ((bcr ^ (br & 7)) << 3)]) =
        *reinterpret_cast<const s8x*>(w + (size_t)(nt * 32 + br) * CCH + kb * 64 + bcr * 8);
    }
    __syncthreads();
    #pragma unroll
    for (int kin = 0; kin < 2; ++kin) {
      const int chx = ((kin * 4 + quad) ^ (l16 & 7)) << 3;
      const s8x a0 = *reinterpret_cast<const s8x*>(&As[(wv * 16 + l16) * 64 + chx]);
      #pragma unroll
      for (int ni = 0; ni < 2; ++ni) {
        const s8x bf = *reinterpret_cast<const s8x*>(&Bs[(ni * 16 + l16) * 64 + chx]);
        acc[ni] = mfma16(a0, bf, acc[ni]);
      }
    }
  }

  const float g0 = gamma[0];
  #pragma unroll
  for (int ni = 0; ni < 2; ++ni) {
    const int c = nt * 32 + ni * 16 + l16;
    const float bs = bias[c];
    const int gr = mt * 64 + wv * 16 + quad * 4;
    const int bb = gr >> 12, n0 = gr & 4095;
    const size_t off = (size_t)(bb * CCH + c) * NSEQ + n0;
    const float4 xv = *reinterpret_cast<const float4*>(x + off);
    float4 ov;
    ov.x = g0 * (acc[ni][0] + bs) + xv.x;
    ov.y = g0 * (acc[ni][1] + bs) + xv.y;
    ov.z = g0 * (acc[ni][2] + bs) + xv.z;
    ov.w = g0 * (acc[ni][3] + bs) + xv.w;
    *reinterpret_cast<float4*>(out + off) = ov;
  }
}

// ---------------- Flash attention: R5 staging + PV-lag (R9, verbatim — 60.8us) ----------------
__global__ __launch_bounds__(256, 4) void fa_kernel(const unsigned short* __restrict__ q,
                                                    const unsigned short* __restrict__ k,
                                                    const unsigned short* __restrict__ vt,
                                                    float* __restrict__ Opart,
                                                    float* __restrict__ Lpart) {
  __shared__ unsigned short Ks[2][64 * 40];   // 2 x 5.0 KiB, kv-rows padded to 40 shorts
  __shared__ unsigned short Vs[2][32 * 72];   // 2 x 4.5 KiB, d-rows padded to 72 shorts
  __shared__ unsigned short Ps[128 * 72];     // 18 KiB, q-rows padded to 72 shorts

  const int tid  = threadIdx.x;
  const int wv   = tid >> 6;
  const int lane = tid & 63;
  const int quad = lane >> 4;
  const int l16  = lane & 15;
  const int i    = blockIdx.x;
  const int bh   = i & 15;          // XCD pinning
  const int rest = i >> 4;          // 0..63
  const int half = rest & 1;
  const int qblk = rest >> 1;       // 0..31
  const int kv0  = half * 2048;     // this block's KV range: [kv0, kv0+2048)

  const unsigned short* kb_ = k  + ((size_t)bh * NSEQ + kv0) * HD;
  const unsigned short* vb_ = vt + (size_t)bh * HD * NSEQ + kv0;

  // cooperative staging assignment (256 threads, 16B each)
  const int krow = tid >> 2;          // 0..63  kv row of K tile
  const int kdc  = (tid & 3) * 8;     // d col (shorts)
  const int vrow = tid >> 3;          // 0..31  d row of V^T tile
  const int vkc  = (tid & 7) * 8;     // kv col (shorts)

  s8x bq0, bq1;
  {
    const unsigned short* qb = q + ((size_t)bh * NSEQ + (size_t)qblk * 128 + wv * 32) * HD;
    bq0 = *reinterpret_cast<const s8x*>(qb + (size_t)l16 * HD + quad * 8);
    bq1 = *reinterpret_cast<const s8x*>(qb + (size_t)(16 + l16) * HD + quad * 8);
  }

  // prologue: stage tile 0, then issue loads for tile 1
  uint4 kreg = *reinterpret_cast<const uint4*>(kb_ + (size_t)krow * HD + kdc);
  uint4 vreg = *reinterpret_cast<const uint4*>(vb_ + (size_t)vrow * NSEQ + vkc);
  *reinterpret_cast<uint4*>(&Ks[0][krow * 40 + kdc]) = kreg;
  *reinterpret_cast<uint4*>(&Vs[0][vrow * 72 + vkc]) = vreg;
  kreg = *reinterpret_cast<const uint4*>(kb_ + (size_t)(64 + krow) * HD + kdc);
  vreg = *reinterpret_cast<const uint4*>(vb_ + (size_t)vrow * NSEQ + 64 + vkc);
  __syncthreads();

  // S(0) from Ks[0]
  f4x st[4][2];
  #pragma unroll
  for (int ii = 0; ii < 4; ++ii) {
    const s8x ak = *reinterpret_cast<const s8x*>(&Ks[0][(ii * 16 + l16) * 40 + quad * 8]);
    const f4x z = {0.f, 0.f, 0.f, 0.f};
    st[ii][0] = mfma16(ak, bq0, z);
    st[ii][1] = mfma16(ak, bq1, z);
  }

  f4x oacc[2][2];
  #pragma unroll
  for (int dt = 0; dt < 2; ++dt)
    #pragma unroll
    for (int ct = 0; ct < 2; ++ct)
      oacc[dt][ct] = (f4x){0.f, 0.f, 0.f, 0.f};
  f4x accL[2] = {(f4x){0.f, 0.f, 0.f, 0.f}, (f4x){0.f, 0.f, 0.f, 0.f}};

  s8x ones;
  #pragma unroll
  for (int j = 0; j < 8; ++j) ones[j] = (short)0x3F80;   // bf16 1.0

  const int r0 = (wv * 32 + l16) * 72;
  const int r1 = (wv * 32 + 16 + l16) * 72;

  s8x vavr[4];   // V(t) fragments carried in regs for next iter's lagged PV

  for (int t = 0; t < 32; ++t) {
    const int c = t & 1;

    // ---- A: read P(t-1) fragments (MUST precede this iter's P writes; in-order LDS) ----
    s8x bp[4];
    if (t > 0) {
      bp[0] = *reinterpret_cast<const s8x*>(&Ps[r0 + 0 * 32 + quad * 8]);
      bp[1] = *reinterpret_cast<const s8x*>(&Ps[r1 + 0 * 32 + quad * 8]);
      bp[2] = *reinterpret_cast<const s8x*>(&Ps[r0 + 1 * 32 + quad * 8]);
      bp[3] = *reinterpret_cast<const s8x*>(&Ps[r1 + 1 * 32 + quad * 8]);
    }

    // ---- B: write staged tile t+1 into the back buffers ----
    if (t + 1 < 32) {
      *reinterpret_cast<uint4*>(&Ks[c ^ 1][krow * 40 + kdc]) = kreg;
      *reinterpret_cast<uint4*>(&Vs[c ^ 1][vrow * 72 + vkc]) = vreg;
    }

    // ---- D: PV(t-1) MFMAs (independent of exp below; overlaps on MFMA pipe) ----
    if (t > 0) {
      #pragma unroll
      for (int kb2 = 0; kb2 < 2; ++kb2) {
        oacc[0][0] = mfma16(vavr[kb2],     bp[2 * kb2],     oacc[0][0]);
        oacc[1][0] = mfma16(vavr[2 + kb2], bp[2 * kb2],     oacc[1][0]);
        oacc[0][1] = mfma16(vavr[kb2],     bp[2 * kb2 + 1], oacc[0][1]);
        oacc[1][1] = mfma16(vavr[2 + kb2], bp[2 * kb2 + 1], oacc[1][1]);
        accL[0] = mfma16(ones, bp[2 * kb2],     accL[0]);
        accL[1] = mfma16(ones, bp[2 * kb2 + 1], accL[1]);
      }
    }

    // ---- C+E: exp(t) + pack + write P(t) (after A in program order: safe) ----
    #pragma unroll
    for (int ct = 0; ct < 2; ++ct) {
      const int prow = (wv * 32 + ct * 16 + l16) * 72;
      #pragma unroll
      for (int ii = 0; ii < 4; ++ii) {
        const float e0 = FEXP2(st[ii][ct][0]);
        const float e1 = FEXP2(st[ii][ct][1]);
        const float e2 = FEXP2(st[ii][ct][2]);
        const float e3 = FEXP2(st[ii][ct][3]);
        uint2 pw;
        pw.x = pk_bf_trunc(e0, e1);
        pw.y = pk_bf_trunc(e2, e3);
        *reinterpret_cast<uint2*>(&Ps[prow + ii * 16 + quad * 4]) = pw;
      }
    }

    // ---- F: issue global loads for tile t+2 (loop-carried: cannot be sunk) ----
    if (t + 2 < 32) {
      kreg = *reinterpret_cast<const uint4*>(kb_ + (size_t)((t + 2) * 64 + krow) * HD + kdc);
      vreg = *reinterpret_cast<const uint4*>(vb_ + (size_t)vrow * NSEQ + (t + 2) * 64 + vkc);
    }

    // ---- G: V(t) fragments -> regs from FRONT buffer (race-free) ----
    #pragma unroll
    for (int kb2 = 0; kb2 < 2; ++kb2) {
      vavr[kb2]     = *reinterpret_cast<const s8x*>(&Vs[c][l16 * 72 + kb2 * 32 + quad * 8]);
      vavr[2 + kb2] = *reinterpret_cast<const s8x*>(&Vs[c][(16 + l16) * 72 + kb2 * 32 + quad * 8]);
    }

    __syncthreads();   // back buffers fully written; fronts fully read

    // ---- I: S(t+1) from the freshly staged K buffer ----
    if (t + 1 < 32) {
      #pragma unroll
      for (int ii = 0; ii < 4; ++ii) {
        const s8x ak = *reinterpret_cast<const s8x*>(&Ks[c ^ 1][(ii * 16 + l16) * 40 + quad * 8]);
        const f4x z = {0.f, 0.f, 0.f, 0.f};
        st[ii][0] = mfma16(ak, bq0, z);
        st[ii][1] = mfma16(ak, bq1, z);
      }
    }
  }

  // ---- epilogue: PV(31) (P(31) in Ps, V(31) in vavr) ----
  {
    s8x bp[4];
    bp[0] = *reinterpret_cast<const s8x*>(&Ps[r0 + 0 * 32 + quad * 8]);
    bp[1] = *reinterpret_cast<const s8x*>(&Ps[r1 + 0 * 32 + quad * 8]);
    bp[2] = *reinterpret_cast<const s8x*>(&Ps[r0 + 1 * 32 + quad * 8]);
    bp[3] = *reinterpret_cast<const s8x*>(&Ps[r1 + 1 * 32 + quad * 8]);
    #pragma unroll
    for (int kb2 = 0; kb2 < 2; ++kb2) {
      oacc[0][0] = mfma16(vavr[kb2],     bp[2 * kb2],     oacc[0][0]);
      oacc[1][0] = mfma16(vavr[2 + kb2], bp[2 * kb2],     oacc[1][0]);
      oacc[0][1] = mfma16(vavr[kb2],     bp[2 * kb2 + 1], oacc[0][1]);
      oacc[1][1] = mfma16(vavr[2 + kb2], bp[2 * kb2 + 1], oacc[1][1]);
      accL[0] = mfma16(ones, bp[2 * kb2],     accL[0]);
      accL[1] = mfma16(ones, bp[2 * kb2 + 1], accL[1]);
    }
  }

  // ---- epilogue: store partial O (f32) and partial l ----
  #pragma unroll
  for (int ct = 0; ct < 2; ++ct) {
    const int qg = qblk * 128 + wv * 32 + ct * 16 + l16;
    float* obase = Opart + ((size_t)(half * 16 + bh) * NSEQ + qg) * HD;
    #pragma unroll
    for (int dt = 0; dt < 2; ++dt) {
      float4 ov;
      ov.x = oacc[dt][ct][0]; ov.y = oacc[dt][ct][1];
      ov.z = oacc[dt][ct][2]; ov.w = oacc[dt][ct][3];
      *reinterpret_cast<float4*>(obase + dt * 16 + quad * 4) = ov;
    }
    if (quad == 0)
      Lpart[(size_t)(half * 16 + bh) * NSEQ + qg] = accL[ct][0];
  }
}

// ---------------- combine the two KV-halves: O=(O0+O1)/(l0+l1), write bf16 xa ----------------
__global__ __launch_bounds__(256) void fa_combine(const float* __restrict__ Opart,
                                                  const float* __restrict__ Lpart,
                                                  unsigned short* __restrict__ xa) {
  const int t  = blockIdx.x * 256 + threadIdx.x;   // 0..262143
  const int c8 = t & 3;                            // col group of 8
  const int n  = (t >> 2) & 4095;
  const int bh = t >> 14;
  const int b  = bh >> 3, h = bh & 7;

  const size_t o0 = ((size_t)bh * NSEQ + n) * HD + c8 * 8;
  const size_t o1 = o0 + (size_t)16 * NSEQ * HD;
  const float4 a0 = *reinterpret_cast<const float4*>(Opart + o0);
  const float4 a1 = *reinterpret_cast<const float4*>(Opart + o0 + 4);
  const float4 b0 = *reinterpret_cast<const float4*>(Opart + o1);
  const float4 b1 = *reinterpret_cast<const float4*>(Opart + o1 + 4);
  const float l0 = Lpart[(size_t)bh * NSEQ + n];
  const float l1 = Lpart[(size_t)(16 + bh) * NSEQ + n];
  const float rl = 1.f / (l0 + l1);

  uint4 ow;
  ow.x = pk_bf_rnd((a0.x + b0.x) * rl, (a0.y + b0.y) * rl);
  ow.y = pk_bf_rnd((a0.z + b0.z) * rl, (a0.w + b0.w) * rl);
  ow.z = pk_bf_rnd((a1.x + b1.x) * rl, (a1.y + b1.y) * rl);
  ow.w = pk_bf_rnd((a1.z + b1.z) * rl, (a1.w + b1.w) * rl);
  *reinterpret_cast<uint4*>(xa + ((size_t)b * NSEQ + n) * CCH + h * HD + c8 * 8) = ow;
}

extern "C" void kernel_launch(void* const* d_in, const int* in_sizes, int n_in,
                              void* d_out, int out_size, void* d_ws, size_t ws_size,
                              hipStream_t stream) {
  const float* x      = (const float*)d_in[0];
  const float* norm_w = (const float*)d_in[1];
  const float* norm_b = (const float*)d_in[2];
  const float* qkv_w  = (const float*)d_in[3];
  const float* qkv_b  = (const float*)d_in[4];
  const float* proj_w = (const float*)d_in[5];
  const float* proj_b = (const float*)d_in[6];
  const float* gamma  = (const float*)d_in[7];
  float* out = (float*)d_out;

  char* ws = (char*)d_ws;
  unsigned short* xn  = (unsigned short*)(ws);              // (B,N,C) bf16, 4 MiB
  unsigned short* qwb = (unsigned short*)(ws + 4194304);
  unsigned short* pwb = (unsigned short*)(ws + 4587520);
  unsigned short* q   = (unsigned short*)(ws + 4718592);    // (B,NH,N,HD), pre-scaled
  unsigned short* k   = (unsigned short*)(ws + 8912896);    // (B,NH,N,HD)
  unsigned short* vt  = (unsigned short*)(ws + 13107200);   // (B,NH,HD,N)
  unsigned short* xa  = (unsigned short*)(ws + 17301504);   // (B,N,C) bf16, 4 MiB
  float* Opart        = (float*)(ws + 21495808);            // [2][16][N][HD] f32, 16 MiB
  float* Lpart        = (float*)(ws + 38273024);            // [2][16][N] f32, 512 KiB

  hipLaunchKernelGGL(ln_cvt_kernel, dim3(512), dim3(256), 0, stream,
                     x, norm_w, norm_b, xn, qkv_w, proj_w, qwb, pwb);
  hipLaunchKernelGGL(qkv_gemm,  dim3(128, 12), dim3(256), 0, stream, xn, qwb, qkv_b, q, k, vt);
  hipLaunchKernelGGL(fa_kernel, dim3(1024), dim3(256), 0, stream, q, k, vt, Opart, Lpart);
  hipLaunchKernelGGL(fa_combine, dim3(1024), dim3(256), 0, stream, Opart, Lpart, xa);
  hipLaunchKernelGGL(proj_gemm, dim3(128, 8), dim3(256), 0, stream, xa, pwb, proj_b, gamma, x, out);
}

// Round 11
// 143.182 us; speedup vs baseline: 1.2100x; 1.0276x over previous
//
#include <hip/hip_runtime.h>

#define CCH   256
#define NSEQ  4096
#define NH    8
#define HD    32

typedef short s8x __attribute__((ext_vector_type(8)));
typedef float f4x __attribute__((ext_vector_type(4)));

__device__ __forceinline__ f4x mfma16(s8x a, s8x b, f4x c) {
  return __builtin_amdgcn_mfma_f32_16x16x32_bf16(a, b, c, 0, 0, 0);
}

__device__ __forceinline__ unsigned short f2bf(float f) {
  union { float f; unsigned int u; } v; v.f = f;
  unsigned int u = v.u + 0x7fffu + ((v.u >> 16) & 1u);
  return (unsigned short)(u >> 16);
}

__device__ __forceinline__ unsigned int pk_bf_rnd(float lo, float hi) {
  return (unsigned int)f2bf(lo) | ((unsigned int)f2bf(hi) << 16);
}

// pack two f32 -> one u32 of bf16 (truncating; P >= 0 so safe)
__device__ __forceinline__ unsigned int pk_bf_trunc(float lo, float hi) {
  union { float f; unsigned int u; } a, b; a.f = lo; b.f = hi;
  return __builtin_amdgcn_perm(b.u, a.u, 0x07060302);
}

// raw v_exp_f32
#if defined(__has_builtin)
#if __has_builtin(__builtin_amdgcn_exp2f)
#define FEXP2(x) __builtin_amdgcn_exp2f(x)
#endif
#endif
#ifndef FEXP2
__device__ __forceinline__ float __fexp2_asm(float x) {
  float r; asm("v_exp_f32 %0, %1" : "=v"(r) : "v"(x)); return r;
}
#define FEXP2(x) __fexp2_asm(x)
#endif

#define C2SCALE (0.17677669529663689f * 1.4426950408889634f)

// ---------------- LayerNorm + transpose, with cvt_weights folded in ----------------
__global__ __launch_bounds__(256) void ln_cvt_kernel(const float* __restrict__ x,
                                                     const float* __restrict__ nw,
                                                     const float* __restrict__ nb,
                                                     unsigned short* __restrict__ xn,
                                                     const float* __restrict__ qw,
                                                     const float* __restrict__ pw,
                                                     unsigned short* __restrict__ qwb,
                                                     unsigned short* __restrict__ pwb) {
  if (blockIdx.x >= 256) {
    const int t = (blockIdx.x - 256) * 256 + threadIdx.x;   // 0..65535
    const float4* src;
    unsigned short* dst;
    int idx;
    if (t < 49152) { src = reinterpret_cast<const float4*>(qw); dst = qwb; idx = t; }
    else           { src = reinterpret_cast<const float4*>(pw); dst = pwb; idx = t - 49152; }
    const float4 vv = src[idx];
    union { unsigned short u[4]; uint2 v; } pk;
    pk.u[0] = f2bf(vv.x); pk.u[1] = f2bf(vv.y); pk.u[2] = f2bf(vv.z); pk.u[3] = f2bf(vv.w);
    *reinterpret_cast<uint2*>(dst + 4 * idx) = pk.v;
    return;
  }

  __shared__ float Ls[256 * 32];
  __shared__ float Sred[2][32][8];
  __shared__ float Mrs[32][2];
  const int t  = threadIdx.x;
  const int n  = t & 31;
  const int cg = t >> 5;
  const int p0 = blockIdx.x * 32;
  const int b  = p0 >> 12;
  const int n0 = p0 & 4095;
  const float* xb = x + (size_t)b * CCH * NSEQ + n0;

  #pragma unroll
  for (int i = 0; i < 32; ++i) {
    const int c = i * 8 + cg;
    Ls[c * 32 + (n ^ (c & 31))] = xb[(size_t)c * NSEQ + n];
  }
  __syncthreads();

  float s = 0.f, sq = 0.f;
  #pragma unroll
  for (int j = 0; j < 32; ++j) {
    const int c = cg * 32 + j;
    const float v = Ls[c * 32 + (n ^ j)];
    s += v; sq += v * v;
  }
  Sred[0][n][cg] = s; Sred[1][n][cg] = sq;
  __syncthreads();
  float ts = 0.f, tq = 0.f;
  #pragma unroll
  for (int g = 0; g < 8; ++g) { ts += Sred[0][n][g]; tq += Sred[1][n][g]; }
  const float mean = ts * (1.f / 256.f);
  const float rstd = rsqrtf(tq * (1.f / 256.f) - mean * mean + 1e-5f);
  if (cg == 0) { Mrs[n][0] = mean; Mrs[n][1] = rstd; }
  __syncthreads();

  // coalesced write phase: thread -> (row n2, col-block c8b)
  const int n2  = t >> 3;        // 0..31
  const int c8b = t & 7;
  const float mean2 = Mrs[n2][0];
  const float rstd2 = Mrs[n2][1];
  unsigned short* orow = xn + ((size_t)b * NSEQ + n0 + n2) * CCH;
  #pragma unroll
  for (int j8 = 0; j8 < 4; ++j8) {
    const int cb = (j8 * 8 + c8b) * 8;        // 0..248, step 8
    unsigned int w_[4];
    #pragma unroll
    for (int hw = 0; hw < 4; ++hw) {
      const int c = cb + hw * 2;
      const float v0 = Ls[c * 32 + (n2 ^ (c & 31))];
      const float v1 = Ls[(c + 1) * 32 + (n2 ^ ((c + 1) & 31))];
      const float y0 = (v0 - mean2) * rstd2 * nw[c] + nb[c];
      const float y1 = (v1 - mean2) * rstd2 * nw[c + 1] + nb[c + 1];
      w_[hw] = pk_bf_rnd(y0, y1);
    }
    uint4 pkv; pkv.x = w_[0]; pkv.y = w_[1]; pkv.z = w_[2]; pkv.w = w_[3];
    *reinterpret_cast<uint4*>(orow + cb) = pkv;
  }
}

// ---------------- QKV GEMM: 64x64 tiles (R10 state) ----------------
__global__ __launch_bounds__(256, 6) void qkv_gemm(const unsigned short* __restrict__ xn,
                                                   const unsigned short* __restrict__ w,
                                                   const float* __restrict__ bias,
                                                   unsigned short* __restrict__ q,
                                                   unsigned short* __restrict__ k,
                                                   unsigned short* __restrict__ vt) {
  __shared__ unsigned short As[64 * 64];
  __shared__ unsigned short Bs[64 * 64];
  const int tid = threadIdx.x;
  const int wv  = tid >> 6;
  const int lane = tid & 63;
  const int quad = lane >> 4, l16 = lane & 15;
  const int mt = blockIdx.x;   // 0..127
  const int nt = blockIdx.y;   // 0..11

  f4x acc[4];
  #pragma unroll
  for (int ni = 0; ni < 4; ++ni)
    acc[ni] = (f4x){0.f, 0.f, 0.f, 0.f};

  for (int kb = 0; kb < 4; ++kb) {
    if (kb) __syncthreads();
    #pragma unroll
    for (int j = 0; j < 2; ++j) {
      const int c = j * 256 + tid;
      const int ar = c >> 3, acr = c & 7;
      *reinterpret_cast<s8x*>(&As[ar * 64 + ((acr ^ (ar & 7)) << 3)]) =
        *reinterpret_cast<const s8x*>(xn + (size_t)(mt * 64 + ar) * CCH + kb * 64 + acr * 8);
    }
    #pragma unroll
    for (int j = 0; j < 2; ++j) {
      const int c = j * 256 + tid;
      const int br = c >> 3, bcr = c & 7;
      *reinterpret_cast<s8x*>(&Bs[br * 64 + ((bcr ^ (br & 7)) << 3)]) =
        *reinterpret_cast<const s8x*>(w + (size_t)(nt * 64 + br) * CCH + kb * 64 + bcr * 8);
    }
    __syncthreads();
    #pragma unroll
    for (int kin = 0; kin < 2; ++kin) {
      const int chx = ((kin * 4 + quad) ^ (l16 & 7)) << 3;
      const s8x a0 = *reinterpret_cast<const s8x*>(&As[(wv * 16 + l16) * 64 + chx]);
      #pragma unroll
      for (int ni = 0; ni < 4; ++ni) {
        const s8x bf = *reinterpret_cast<const s8x*>(&Bs[(ni * 16 + l16) * 64 + chx]);
        acc[ni] = mfma16(a0, bf, acc[ni]);
      }
    }
  }

  const int sel = nt >> 2;                  // wave-uniform: 0=q 1=k 2=v
  #pragma unroll
  for (int ni = 0; ni < 4; ++ni) {
    const int o = nt * 64 + ni * 16 + l16;
    const float bs = bias[o];
    const int ol = o & 255;
    const int head = ol >> 5, d = ol & 31;
    const int g0 = mt * 64 + wv * 16 + quad * 4;
    const int bb = g0 >> 12, n0 = g0 & 4095;
    if (sel == 2) {
      unsigned short* vp = vt + ((size_t)(bb * NH + head) * HD + d) * NSEQ + n0;
      uint2 pk;
      pk.x = pk_bf_rnd(acc[ni][0] + bs, acc[ni][1] + bs);
      pk.y = pk_bf_rnd(acc[ni][2] + bs, acc[ni][3] + bs);
      *reinterpret_cast<uint2*>(vp) = pk;
    } else {
      const float sc = (sel == 0) ? C2SCALE : 1.f;
      unsigned short* base = (sel == 0) ? q : k;
      #pragma unroll
      for (int r = 0; r < 4; ++r)
        base[((size_t)(bb * NH + head) * NSEQ + n0 + r) * HD + d] = f2bf((acc[ni][r] + bs) * sc);
    }
  }
}

// ---------------- proj GEMM + residual: 64x32 tiles (R10 state) ----------------
__global__ __launch_bounds__(256, 6) void proj_gemm(const unsigned short* __restrict__ xa,
                                                    const unsigned short* __restrict__ w,
                                                    const float* __restrict__ bias,
                                                    const float* __restrict__ gamma,
                                                    const float* __restrict__ x,
                                                    float* __restrict__ out) {
  __shared__ unsigned short As[64 * 64];
  __shared__ unsigned short Bs[32 * 64];
  const int tid = threadIdx.x;
  const int wv  = tid >> 6;
  const int lane = tid & 63;
  const int quad = lane >> 4, l16 = lane & 15;
  const int mt = blockIdx.x;   // 0..127
  const int nt = blockIdx.y;   // 0..7

  f4x acc[2];
  acc[0] = (f4x){0.f, 0.f, 0.f, 0.f};
  acc[1] = (f4x){0.f, 0.f, 0.f, 0.f};

  for (int kb = 0; kb < 4; ++kb) {
    if (kb) __syncthreads();
    #pragma unroll
    for (int j = 0; j < 2; ++j) {
      const int c = j * 256 + tid;
      const int ar = c >> 3, acr = c & 7;
      *reinterpret_cast<s8x*>(&As[ar * 64 + ((acr ^ (ar & 7)) << 3)]) =
        *reinterpret_cast<const s8x*>(xa + (size_t)(mt * 64 + ar) * CCH + kb * 64 + acr * 8);
    }
    {
      const int c = tid;                      // 32*64 shorts = exactly 1 s8x/thread
      const int br = c >> 3, bcr = c & 7;
      *reinterpret_cast<s8x*>(&Bs[br * 64 + ((bcr ^ (br & 7)) << 3)]) =
        *reinterpret_cast<const s8x*>(w + (size_t)(nt * 32 + br) * CCH + kb * 64 + bcr * 8);
    }
    __syncthreads();
    #pragma unroll
    for (int kin = 0; kin < 2; ++kin) {
      const int chx = ((kin * 4 + quad) ^ (l16 & 7)) << 3;
      const s8x a0 = *reinterpret_cast<const s8x*>(&As[(wv * 16 + l16) * 64 + chx]);
      #pragma unroll
      for (int ni = 0; ni < 2; ++ni) {
        const s8x bf = *reinterpret_cast<const s8x*>(&Bs[(ni * 16 + l16) * 64 + chx]);
        acc[ni] = mfma16(a0, bf, acc[ni]);
      }
    }
  }

  const float g0 = gamma[0];
  #pragma unroll
  for (int ni = 0; ni < 2; ++ni) {
    const int c = nt * 32 + ni * 16 + l16;
    const float bs = bias[c];
    const int gr = mt * 64 + wv * 16 + quad * 4;
    const int bb = gr >> 12, n0 = gr & 4095;
    const size_t off = (size_t)(bb * CCH + c) * NSEQ + n0;
    const float4 xv = *reinterpret_cast<const float4*>(x + off);
    float4 ov;
    ov.x = g0 * (acc[ni][0] + bs) + xv.x;
    ov.y = g0 * (acc[ni][1] + bs) + xv.y;
    ov.z = g0 * (acc[ni][2] + bs) + xv.z;
    ov.w = g0 * (acc[ni][3] + bs) + xv.w;
    *reinterpret_cast<float4*>(out + off) = ov;
  }
}

// ---------------- Flash attention: R9 pipeline + fragment-major LDS (R11) ----------------
// R10 counters: SQ_LDS_BANK_CONFLICT=1.15e7/dispatch = ~1400 conflict-cyc per CU-iter
// vs ~4500 wall = ~30% of fa in LDS serialization. Cause: all MFMA fragment reads
// (16 rows x 4 col-slots) have bank index forced to multiples of 4 (rows 16B-aligned)
// -> 8 banks/instr. No padding/XOR can fix (stride/4 always even).
// R11 fix: FRAGMENT-MAJOR layouts. K/V/P stored in exact fragment-read order:
// slot = (frag*64 + lane)*16B -> every fragment read AND staging write is a
// contiguous 1KB wave access (conflict-free floor). Staging threads re-assigned
// so thread tid loads the GLOBAL element of fragment-slot tid (per-lane global
// addrs free; 64B lines still fully covered). P writes become 4-way b64 (cheap);
// P reads conflict-free. LDS 37.9->32KB. Bit-identical math; R9 structure kept.
__global__ __launch_bounds__(256, 4) void fa_kernel(const unsigned short* __restrict__ q,
                                                    const unsigned short* __restrict__ k,
                                                    const unsigned short* __restrict__ vt,
                                                    float* __restrict__ Opart,
                                                    float* __restrict__ Lpart) {
  __shared__ unsigned short Kf[2][2048];   // 4 frags x 64 lanes x 8 shorts, 4KB each
  __shared__ unsigned short Vf[2][2048];   // 4 frags x 64 lanes x 8 shorts
  __shared__ unsigned short Pf[8192];      // 4 waves x 4 frags x 64 lanes x 8 shorts, 16KB

  const int tid  = threadIdx.x;
  const int wv   = tid >> 6;
  const int lane = tid & 63;
  const int quad = lane >> 4;
  const int l16  = lane & 15;
  const int i    = blockIdx.x;
  const int bh   = i & 15;          // XCD pinning
  const int rest = i >> 4;          // 0..63
  const int half = rest & 1;
  const int qblk = rest >> 1;       // 0..31
  const int kv0  = half * 2048;     // this block's KV range: [kv0, kv0+2048)

  const unsigned short* kb_ = k  + ((size_t)bh * NSEQ + kv0) * HD;
  const unsigned short* vb_ = vt + (size_t)bh * HD * NSEQ + kv0;

  // staging assignment: thread tid <-> fragment slot tid
  // K: frag ii = tid>>6, lane' = tid&63 -> global row ii*16 + (tid&15), col ((tid>>4)&3)*8
  const int kfrow = (tid >> 6) * 16 + (tid & 15);
  const int kfcol = ((tid >> 4) & 3) * 8;
  // V: frag f = tid>>6 = h*2+kb2 -> global d-row h*16 + (tid&15), kv-col kb2*32 + ((tid>>4)&3)*8
  const int vfrow = ((tid >> 7) & 1) * 16 + (tid & 15);
  const int vfcol = ((tid >> 6) & 1) * 32 + ((tid >> 4) & 3) * 8;

  s8x bq0, bq1;
  {
    const unsigned short* qb = q + ((size_t)bh * NSEQ + (size_t)qblk * 128 + wv * 32) * HD;
    bq0 = *reinterpret_cast<const s8x*>(qb + (size_t)l16 * HD + quad * 8);
    bq1 = *reinterpret_cast<const s8x*>(qb + (size_t)(16 + l16) * HD + quad * 8);
  }

  // prologue: stage tile 0, then issue loads for tile 1
  uint4 kreg = *reinterpret_cast<const uint4*>(kb_ + (size_t)kfrow * HD + kfcol);
  uint4 vreg = *reinterpret_cast<const uint4*>(vb_ + (size_t)vfrow * NSEQ + vfcol);
  *reinterpret_cast<uint4*>(&Kf[0][tid * 8]) = kreg;
  *reinterpret_cast<uint4*>(&Vf[0][tid * 8]) = vreg;
  kreg = *reinterpret_cast<const uint4*>(kb_ + (size_t)(64 + kfrow) * HD + kfcol);
  vreg = *reinterpret_cast<const uint4*>(vb_ + (size_t)vfrow * NSEQ + 64 + vfcol);
  __syncthreads();

  // S(0) from Kf[0]
  f4x st[4][2];
  #pragma unroll
  for (int ii = 0; ii < 4; ++ii) {
    const s8x ak = *reinterpret_cast<const s8x*>(&Kf[0][(ii * 64 + lane) * 8]);
    const f4x z = {0.f, 0.f, 0.f, 0.f};
    st[ii][0] = mfma16(ak, bq0, z);
    st[ii][1] = mfma16(ak, bq1, z);
  }

  f4x oacc[2][2];
  #pragma unroll
  for (int dt = 0; dt < 2; ++dt)
    #pragma unroll
    for (int ct = 0; ct < 2; ++ct)
      oacc[dt][ct] = (f4x){0.f, 0.f, 0.f, 0.f};
  f4x accL[2] = {(f4x){0.f, 0.f, 0.f, 0.f}, (f4x){0.f, 0.f, 0.f, 0.f}};

  s8x ones;
  #pragma unroll
  for (int j = 0; j < 8; ++j) ones[j] = (short)0x3F80;   // bf16 1.0

  const int pbase = wv * 4 * 64 * 8;   // this wave's Pf region (shorts)

  s8x vavr[4];   // V(t) fragments carried in regs for next iter's lagged PV

  for (int t = 0; t < 32; ++t) {
    const int c = t & 1;

    // ---- A: read P(t-1) fragments (precede this iter's P writes; in-order LDS) ----
    s8x bp[4];
    if (t > 0) {
      #pragma unroll
      for (int j = 0; j < 4; ++j)
        bp[j] = *reinterpret_cast<const s8x*>(&Pf[pbase + (j * 64 + lane) * 8]);
    }

    // ---- B: write staged tile t+1 into the back buffers (contiguous 1KB/wave) ----
    if (t + 1 < 32) {
      *reinterpret_cast<uint4*>(&Kf[c ^ 1][tid * 8]) = kreg;
      *reinterpret_cast<uint4*>(&Vf[c ^ 1][tid * 8]) = vreg;
    }

    // ---- D: PV(t-1) MFMAs (independent of exp below; overlaps on MFMA pipe) ----
    if (t > 0) {
      #pragma unroll
      for (int kb2 = 0; kb2 < 2; ++kb2) {
        oacc[0][0] = mfma16(vavr[kb2],     bp[2 * kb2],     oacc[0][0]);
        oacc[1][0] = mfma16(vavr[2 + kb2], bp[2 * kb2],     oacc[1][0]);
        oacc[0][1] = mfma16(vavr[kb2],     bp[2 * kb2 + 1], oacc[0][1]);
        oacc[1][1] = mfma16(vavr[2 + kb2], bp[2 * kb2 + 1], oacc[1][1]);
        accL[0] = mfma16(ones, bp[2 * kb2],     accL[0]);
        accL[1] = mfma16(ones, bp[2 * kb2 + 1], accL[1]);
      }
    }

    // ---- C+E: exp(t) + pack + write P(t) fragment-major (after A: safe) ----
    #pragma unroll
    for (int ct = 0; ct < 2; ++ct) {
      #pragma unroll
      for (int ii = 0; ii < 4; ++ii) {
        const float e0 = FEXP2(st[ii][ct][0]);
        const float e1 = FEXP2(st[ii][ct][1]);
        const float e2 = FEXP2(st[ii][ct][2]);
        const float e3 = FEXP2(st[ii][ct][3]);
        uint2 pw;
        pw.x = pk_bf_trunc(e0, e1);
        pw.y = pk_bf_trunc(e2, e3);
        // frag f = (ii>>1)*2 + ct; lane' = ((ii&1)*2 + (quad>>1))*16 + l16; piece = (quad&1)*4
        const int paddr = pbase + (((ii >> 1) * 2 + ct) * 64 + ((ii & 1) * 2 + (quad >> 1)) * 16 + l16) * 8 + (quad & 1) * 4;
        *reinterpret_cast<uint2*>(&Pf[paddr]) = pw;
      }
    }

    // ---- F: issue global loads for tile t+2 (loop-carried: cannot be sunk) ----
    if (t + 2 < 32) {
      kreg = *reinterpret_cast<const uint4*>(kb_ + (size_t)((t + 2) * 64 + kfrow) * HD + kfcol);
      vreg = *reinterpret_cast<const uint4*>(vb_ + (size_t)vfrow * NSEQ + (t + 2) * 64 + vfcol);
    }

    // ---- G: V(t) fragments -> regs from FRONT buffer (race-free, contiguous) ----
    #pragma unroll
    for (int j = 0; j < 4; ++j)
      vavr[j] = *reinterpret_cast<const s8x*>(&Vf[c][(j * 64 + lane) * 8]);

    __syncthreads();   // back buffers fully written; fronts fully read

    // ---- I: S(t+1) from the freshly staged K buffer ----
    if (t + 1 < 32) {
      #pragma unroll
      for (int ii = 0; ii < 4; ++ii) {
        const s8x ak = *reinterpret_cast<const s8x*>(&Kf[c ^ 1][(ii * 64 + lane) * 8]);
        const f4x z = {0.f, 0.f, 0.f, 0.f};
        st[ii][0] = mfma16(ak, bq0, z);
        st[ii][1] = mfma16(ak, bq1, z);
      }
    }
  }

  // ---- epilogue: PV(31) (P(31) in Pf, V(31) in vavr) ----
  {
    s8x bp[4];
    #pragma unroll
    for (int j = 0; j < 4; ++j)
      bp[j] = *reinterpret_cast<const s8x*>(&Pf[pbase + (j * 64 + lane) * 8]);
    #pragma unroll
    for (int kb2 = 0; kb2 < 2; ++kb2) {
      oacc[0][0] = mfma16(vavr[kb2],     bp[2 * kb2],     oacc[0][0]);
      oacc[1][0] = mfma16(vavr[2 + kb2], bp[2 * kb2],     oacc[1][0]);
      oacc[0][1] = mfma16(vavr[kb2],     bp[2 * kb2 + 1], oacc[0][1]);
      oacc[1][1] = mfma16(vavr[2 + kb2], bp[2 * kb2 + 1], oacc[1][1]);
      accL[0] = mfma16(ones, bp[2 * kb2],     accL[0]);
      accL[1] = mfma16(ones, bp[2 * kb2 + 1], accL[1]);
    }
  }

  // ---- epilogue: store partial O (f32) and partial l ----
  #pragma unroll
  for (int ct = 0; ct < 2; ++ct) {
    const int qg = qblk * 128 + wv * 32 + ct * 16 + l16;
    float* obase = Opart + ((size_t)(half * 16 + bh) * NSEQ + qg) * HD;
    #pragma unroll
    for (int dt = 0; dt < 2; ++dt) {
      float4 ov;
      ov.x = oacc[dt][ct][0]; ov.y = oacc[dt][ct][1];
      ov.z = oacc[dt][ct][2]; ov.w = oacc[dt][ct][3];
      *reinterpret_cast<float4*>(obase + dt * 16 + quad * 4) = ov;
    }
    if (quad == 0)
      Lpart[(size_t)(half * 16 + bh) * NSEQ + qg] = accL[ct][0];
  }
}

// ---------------- combine the two KV-halves: O=(O0+O1)/(l0+l1), write bf16 xa ----------------
__global__ __launch_bounds__(256) void fa_combine(const float* __restrict__ Opart,
                                                  const float* __restrict__ Lpart,
                                                  unsigned short* __restrict__ xa) {
  const int t  = blockIdx.x * 256 + threadIdx.x;   // 0..262143
  const int c8 = t & 3;                            // col group of 8
  const int n  = (t >> 2) & 4095;
  const int bh = t >> 14;
  const int b  = bh >> 3, h = bh & 7;

  const size_t o0 = ((size_t)bh * NSEQ + n) * HD + c8 * 8;
  const size_t o1 = o0 + (size_t)16 * NSEQ * HD;
  const float4 a0 = *reinterpret_cast<const float4*>(Opart + o0);
  const float4 a1 = *reinterpret_cast<const float4*>(Opart + o0 + 4);
  const float4 b0 = *reinterpret_cast<const float4*>(Opart + o1);
  const float4 b1 = *reinterpret_cast<const float4*>(Opart + o1 + 4);
  const float l0 = Lpart[(size_t)bh * NSEQ + n];
  const float l1 = Lpart[(size_t)(16 + bh) * NSEQ + n];
  const float rl = 1.f / (l0 + l1);

  uint4 ow;
  ow.x = pk_bf_rnd((a0.x + b0.x) * rl, (a0.y + b0.y) * rl);
  ow.y = pk_bf_rnd((a0.z + b0.z) * rl, (a0.w + b0.w) * rl);
  ow.z = pk_bf_rnd((a1.x + b1.x) * rl, (a1.y + b1.y) * rl);
  ow.w = pk_bf_rnd((a1.z + b1.z) * rl, (a1.w + b1.w) * rl);
  *reinterpret_cast<uint4*>(xa + ((size_t)b * NSEQ + n) * CCH + h * HD + c8 * 8) = ow;
}

extern "C" void kernel_launch(void* const* d_in, const int* in_sizes, int n_in,
                              void* d_out, int out_size, void* d_ws, size_t ws_size,
                              hipStream_t stream) {
  const float* x      = (const float*)d_in[0];
  const float* norm_w = (const float*)d_in[1];
  const float* norm_b = (const float*)d_in[2];
  const float* qkv_w  = (const float*)d_in[3];
  const float* qkv_b  = (const float*)d_in[4];
  const float* proj_w = (const float*)d_in[5];
  const float* proj_b = (const float*)d_in[6];
  const float* gamma  = (const float*)d_in[7];
  float* out = (float*)d_out;

  char* ws = (char*)d_ws;
  unsigned short* xn  = (unsigned short*)(ws);              // (B,N,C) bf16, 4 MiB
  unsigned short* qwb = (unsigned short*)(ws + 4194304);
  unsigned short* pwb = (unsigned short*)(ws + 4587520);
  unsigned short* q   = (unsigned short*)(ws + 4718592);    // (B,NH,N,HD), pre-scaled
  unsigned short* k   = (unsigned short*)(ws + 8912896);    // (B,NH,N,HD)
  unsigned short* vt  = (unsigned short*)(ws + 13107200);   // (B,NH,HD,N)
  unsigned short* xa  = (unsigned short*)(ws + 17301504);   // (B,N,C) bf16, 4 MiB
  float* Opart        = (float*)(ws + 21495808);            // [2][16][N][HD] f32, 16 MiB
  float* Lpart        = (float*)(ws + 38273024);            // [2][16][N] f32, 512 KiB

  hipLaunchKernelGGL(ln_cvt_kernel, dim3(512), dim3(256), 0, stream,
                     x, norm_w, norm_b, xn, qkv_w, proj_w, qwb, pwb);
  hipLaunchKernelGGL(qkv_gemm,  dim3(128, 12), dim3(256), 0, stream, xn, qwb, qkv_b, q, k, vt);
  hipLaunchKernelGGL(fa_kernel, dim3(1024), dim3(256), 0, stream, q, k, vt, Opart, Lpart);
  hipLaunchKernelGGL(fa_combine, dim3(1024), dim3(256), 0, stream, Opart, Lpart, xa);
  hipLaunchKernelGGL(proj_gemm, dim3(128, 8), dim3(256), 0, stream, xa, pwb, proj_b, gamma, x, out);
}